// Round 4
// baseline (95105.566 us; speedup 1.0000x reference)
//
#include <hip/hip_runtime.h>
#include <stdint.h>

typedef unsigned short u16;
typedef __attribute__((ext_vector_type(8))) short short8;
typedef __attribute__((ext_vector_type(4))) float f32x4;

#define BB 256
#define SS 128
#define TT 128
#define EE 512
#define HH 1024
#define VV 256

#define BK 64
#define LDSP 72   // padded LDS row length in bf16 elems (144 B = 9*16, keeps 16B alignment)
#define CH 8      // encoder pre-GEMM chunk (timesteps)

__device__ __forceinline__ float bf2f(u16 u){
    union { unsigned int i; float f; } v; v.i = ((unsigned int)u) << 16; return v.f;
}
__device__ __forceinline__ u16 f2bf(float f){
    union { float f; unsigned int i; } v; v.f = f;
    return (u16)((v.i + 0x7fffu + ((v.i >> 16) & 1u)) >> 16);
}
__device__ __forceinline__ float rcp_(float x){ return __builtin_amdgcn_rcpf(x); }
__device__ __forceinline__ float sigm_(float x){ return rcp_(1.f + __expf(-x)); }
__device__ __forceinline__ float tanh_(float x){ return 1.f - 2.f*rcp_(__expf(2.f*x) + 1.f); }

struct GArgs {
    const u16* A;  const u16* A2; long lda;     // A (M,K) bf16 hi / lo
    const u16* Bw; const u16* B2; long K;       // B (N,K) bf16 hi / lo, ldb == K
    const float* bias;                          // len N (indexed by col), nullable
    u16* Cb; float* Cf; long ldc;               // stores
    const u16* pre; long ldpre;                 // LSTM: add pre[row,col], nullable
    float* cst; long hid;                       // LSTM: c state f32 | MODE3: qp dest + ld
    u16* h1; u16* h1l; long ldh1;               // LSTM: h dest (+lo if split)
    u16* h2; u16* h2l; long ldh2;               // LSTM: optional 2nd h dest
};

// MODE: 0 = store bf16, 1 = store f32, 2 = fused LSTM cell (gate-interleaved cols),
//       3 = dual f32 store (col<256 -> Cf/ldc, col>=256 -> cst/hid)
template<int BMW, int BNW, int MODE, int SPLIT>
__device__ __forceinline__ void gemm_core(const GArgs& g)
{
    constexpr int BM = BMW*64, BN = BNW*64;
    constexpr int NT = BMW*BNW*64;
    constexpr int AE = BM*LDSP, BE = BN*LDSP;
    constexpr int AI = BM*8/NT, BI = BN*8/NT;
    static_assert((BM*8) % NT == 0 && (BN*8) % NT == 0, "staging");
    __shared__ __align__(16) u16 sA[(SPLIT+1)*AE];
    __shared__ __align__(16) u16 sB[(SPLIT+1)*BE];
    const int tid = threadIdx.x;
    const int lane = tid & 63, wave = tid >> 6;
    const int wn = wave % BNW, wm = wave / BNW;
    const int l15 = lane & 15, quad = lane >> 4;
    const long m0 = (long)blockIdx.y * BM, n0 = (long)blockIdx.x * BN;

    f32x4 acc[4][4];
    #pragma unroll
    for (int a=0;a<4;a++)
    #pragma unroll
    for (int c=0;c<4;c++){ f32x4 z = {0.f,0.f,0.f,0.f}; acc[a][c] = z; }

    // register prefetch buffers (iter k+1 fetched during iter k's MFMA block)
    int4 pa[AI], pb[BI];
    int4 pa2[SPLIT ? AI : 1], pb2[SPLIT ? BI : 1];
    auto fetch = [&](long k0){
        #pragma unroll
        for (int i=0;i<AI;i++){
            int c = tid + i*NT; int r = c >> 3, c8 = (c & 7)*8;
            pa[i] = *(const int4*)(g.A + (m0 + r)*g.lda + k0 + c8);
            if (SPLIT) pa2[i] = *(const int4*)(g.A2 + (m0 + r)*g.lda + k0 + c8);
        }
        #pragma unroll
        for (int i=0;i<BI;i++){
            int c = tid + i*NT; int r = c >> 3, c8 = (c & 7)*8;
            pb[i] = *(const int4*)(g.Bw + (n0 + r)*g.K + k0 + c8);
            if (SPLIT) pb2[i] = *(const int4*)(g.B2 + (n0 + r)*g.K + k0 + c8);
        }
    };
    fetch(0);

    for (long k0 = 0; k0 < g.K; k0 += BK){
        #pragma unroll
        for (int i=0;i<AI;i++){
            int c = tid + i*NT; int r = c >> 3, c8 = (c & 7)*8;
            *(int4*)&sA[r*LDSP + c8] = pa[i];
            if (SPLIT) *(int4*)&sA[AE + r*LDSP + c8] = pa2[i];
        }
        #pragma unroll
        for (int i=0;i<BI;i++){
            int c = tid + i*NT; int r = c >> 3, c8 = (c & 7)*8;
            *(int4*)&sB[r*LDSP + c8] = pb[i];
            if (SPLIT) *(int4*)&sB[BE + r*LDSP + c8] = pb2[i];
        }
        __syncthreads();
        if (k0 + BK < g.K) fetch(k0 + BK);   // loads fly during MFMA block
        #pragma unroll
        for (int ks = 0; ks < 2; ks++){
            const int ko = ks*32 + quad*8;
            short8 ah[4], bh[4], al[4], bl[4];
            #pragma unroll
            for (int mi=0; mi<4; mi++){
                int ra = (wm*64 + mi*16 + l15)*LDSP + ko;
                ah[mi] = *(const short8*)&sA[ra];
                if (SPLIT) al[mi] = *(const short8*)&sA[AE + ra];
            }
            #pragma unroll
            for (int ni=0; ni<4; ni++){
                int rb = (wn*64 + ni*16 + l15)*LDSP + ko;
                bh[ni] = *(const short8*)&sB[rb];
                if (SPLIT) bl[ni] = *(const short8*)&sB[BE + rb];
            }
            #pragma unroll
            for (int mi=0; mi<4; mi++)
            #pragma unroll
            for (int ni=0; ni<4; ni++){
                acc[mi][ni] = __builtin_amdgcn_mfma_f32_16x16x32_bf16(ah[mi], bh[ni], acc[mi][ni], 0,0,0);
                if (SPLIT){
                    acc[mi][ni] = __builtin_amdgcn_mfma_f32_16x16x32_bf16(al[mi], bh[ni], acc[mi][ni], 0,0,0);
                    acc[mi][ni] = __builtin_amdgcn_mfma_f32_16x16x32_bf16(ah[mi], bl[ni], acc[mi][ni], 0,0,0);
                }
            }
        }
        __syncthreads();
    }

    // epilogue: C/D layout col = lane&15, row = quad*4 + reg  [m89-verified]
    #pragma unroll
    for (int mi=0; mi<4; mi++)
    #pragma unroll
    for (int ni=0; ni<4; ni++)
    #pragma unroll
    for (int r=0; r<4; r++){
        long row = m0 + wm*64 + mi*16 + quad*4 + r;
        long col = n0 + wn*64 + ni*16 + l15;
        float v = acc[mi][ni][r];
        if (g.bias) v += g.bias[col];
        if (MODE == 2){
            if (g.pre) v += bf2f(g.pre[row*g.ldpre + col]);
            // gates interleaved: col = j*4 + q, q in {i,f,g,o}; 4 gates in 4 adjacent lanes
            float gf = __shfl_xor(v, 1);
            float gg = __shfl_xor(v, 2);
            float go = __shfl_xor(v, 3);
            if ((lane & 3) == 0){
                long j = col >> 2;
                float co = g.cst[row*g.hid + j];
                float cn = sigm_(gf)*co + sigm_(v)*tanh_(gg);
                g.cst[row*g.hid + j] = cn;
                float hn = sigm_(go)*tanh_(cn);
                u16 hb = f2bf(hn);
                u16 lb = 0;
                if (SPLIT) lb = f2bf(hn - bf2f(hb));
                g.h1[row*g.ldh1 + j] = hb;
                if (SPLIT) g.h1l[row*g.ldh1 + j] = lb;
                if (g.h2){
                    g.h2[row*g.ldh2 + j] = hb;
                    if (SPLIT) g.h2l[row*g.ldh2 + j] = lb;
                }
            }
        } else if (MODE == 3){
            if (col < 256) g.Cf[row*g.ldc + col] = v;
            else           g.cst[row*g.hid + (col - 256)] = v;
        } else if (MODE == 1){
            g.Cf[row*g.ldc + col] = v;
        } else {
            g.Cb[row*g.ldc + col] = f2bf(v);
        }
    }
}

template<int BMW,int BNW,int MODE,int SPLIT>
__global__ __launch_bounds__(BMW*BNW*64)
void gemm_kernel(GArgs g){ gemm_core<BMW,BNW,MODE,SPLIT>(g); }

// twin launch: blockIdx.z selects (fwd/bwd encoder work in one dispatch)
template<int BMW,int BNW>
__global__ __launch_bounds__(BMW*BNW*64)
void lstm_step2_kernel(GArgs gf, GArgs gb){
    if (blockIdx.z == 0) gemm_core<BMW,BNW,2,0>(gf);
    else                 gemm_core<BMW,BNW,2,0>(gb);
}
template<int BMW,int BNW>
__global__ __launch_bounds__(BMW*BNW*64)
void gemm2_kernel(GArgs ga, GArgs gb){
    if (blockIdx.z == 0) gemm_core<BMW,BNW,0,0>(ga);
    else                 gemm_core<BMW,BNW,0,0>(gb);
}

// ---------------- attention (per decoder step) ----------------
__global__ __launch_bounds__(256)
void attn_kernel(const u16* __restrict__ enc_proj, const u16* __restrict__ enc_out,
                 const float* __restrict__ qp, const float* __restrict__ w2,
                 const float* __restrict__ b2p,
                 const int* __restrict__ src, const int* __restrict__ tgt,
                 const float* __restrict__ dec_embed,
                 float* __restrict__ out1,
                 u16* __restrict__ a0h, u16* __restrict__ a0l, int n)
{
    int b = blockIdx.x;
    int tid = threadIdx.x;
    int lane = tid & 63, wave = tid >> 6;
    __shared__ float sE[SS];
    __shared__ float sAs[SS];
    float qr[16], wr[16];
    const float* qb = qp + (size_t)b*HH;
    #pragma unroll
    for (int j=0;j<8;j++){
        qr[j]   = qb[lane*8 + j];        wr[j]   = w2[lane*8 + j];
        qr[8+j] = qb[512 + lane*8 + j];  wr[8+j] = w2[512 + lane*8 + j];
    }
    float b2 = b2p[0];
    for (int ii=0; ii<32; ii++){
        int s = wave*32 + ii;
        const u16* row = enc_proj + ((size_t)b*SS + s)*HH;
        int4 r0 = *(const int4*)(row + lane*8);
        int4 r1 = *(const int4*)(row + 512 + lane*8);
        const u16* u0 = (const u16*)&r0;
        const u16* u1 = (const u16*)&r1;
        float acc = 0.f;
        #pragma unroll
        for (int j=0;j<8;j++) acc += tanh_(bf2f(u0[j]) + qr[j]) * wr[j];
        #pragma unroll
        for (int j=0;j<8;j++) acc += tanh_(bf2f(u1[j]) + qr[8+j]) * wr[8+j];
        #pragma unroll
        for (int off=32; off; off>>=1) acc += __shfl_xor(acc, off);
        if (lane == 0){
            float e = acc + b2;
            if (src[b*SS + s] == 0) e = -1e30f;
            sE[s] = e;
        }
    }
    __syncthreads();
    if (wave == 0){
        float v0 = sE[lane], v1 = sE[64 + lane];
        float m = fmaxf(v0, v1);
        #pragma unroll
        for (int off=32; off; off>>=1) m = fmaxf(m, __shfl_xor(m, off));
        float p0 = __expf(v0 - m), p1 = __expf(v1 - m);
        float sum = p0 + p1;
        #pragma unroll
        for (int off=32; off; off>>=1) sum += __shfl_xor(sum, off);
        float inv = 1.f / sum;
        float a0 = p0 * inv, a1 = p1 * inv;
        sAs[lane] = a0; sAs[64+lane] = a1;
        float* op = out1 + ((size_t)b*(TT-1) + n)*SS;
        op[lane] = a0; op[64+lane] = a1;
    }
    __syncthreads();
    // ctx = sum_s a[s] * enc_out[b,s,:]
    int c4 = tid*4;
    float av0=0, av1=0, av2=0, av3=0;
    const u16* eb = enc_out + (size_t)b*SS*HH + c4;
    for (int s=0; s<SS; s++){
        float as = sAs[s];
        uint2 u = *(const uint2*)(eb + (size_t)s*HH);
        const u16* pu = (const u16*)&u;
        av0 += as * bf2f(pu[0]);
        av1 += as * bf2f(pu[1]);
        av2 += as * bf2f(pu[2]);
        av3 += as * bf2f(pu[3]);
    }
    u16* ch = a0h + (size_t)b*2560 + 512 + c4;
    u16* cl = a0l + (size_t)b*2560 + 512 + c4;
    float av[4] = {av0,av1,av2,av3};
    #pragma unroll
    for (int k=0;k<4;k++){
        u16 hi = f2bf(av[k]); ch[k] = hi; cl[k] = f2bf(av[k] - bf2f(hi));
    }
    // emb = dec_embed[tgt[b, n]]
    int tok = tgt[b*TT + n];
    const float* ep = dec_embed + (size_t)tok*EE;
    u16* ehp = a0h + (size_t)b*2560;
    u16* elp = a0l + (size_t)b*2560;
    #pragma unroll
    for (int k=0;k<2;k++){
        int e = tid*2 + k;
        float x = ep[e];
        u16 hi = f2bf(x);
        ehp[e] = hi; elp[e] = f2bf(x - bf2f(hi));
    }
}

// ---------------- prep / utility kernels ----------------
__global__ void permute_convert_kernel(const float* __restrict__ s, u16* __restrict__ d,
    int hid, int cols, int dld, int doff, int total){
    int i = blockIdx.x*256 + threadIdx.x;
    if (i >= total) return;
    int p = i / cols, c = i - p*cols;
    int j = p >> 2, q = p & 3;
    d[(size_t)p*dld + doff + c] = f2bf(s[((size_t)q*hid + j)*cols + c]);
}
__global__ void permute_convert_split_kernel(const float* __restrict__ s, u16* __restrict__ dh,
    u16* __restrict__ dl, int hid, int cols, int dld, int doff, int total){
    int i = blockIdx.x*256 + threadIdx.x;
    if (i >= total) return;
    int p = i / cols, c = i - p*cols;
    int j = p >> 2, q = p & 3;
    float x = s[((size_t)q*hid + j)*cols + c];
    u16 hi = f2bf(x);
    dh[(size_t)p*dld + doff + c] = hi;
    dl[(size_t)p*dld + doff + c] = f2bf(x - bf2f(hi));
}
__global__ void permute_bias_kernel(const float* __restrict__ s, float* __restrict__ d, int hid){
    int p = blockIdx.x*256 + threadIdx.x;
    if (p >= 4*hid) return;
    int j = p >> 2, q = p & 3;
    d[p] = s[q*hid + j];
}
__global__ void convert_kernel(const float* __restrict__ s, int sld, int soff,
    u16* __restrict__ d, int dld, int cols, int total){
    int i = blockIdx.x*256 + threadIdx.x;
    if (i >= total) return;
    int r = i / cols, c = i - r*cols;
    d[(size_t)r*dld + c] = f2bf(s[(size_t)r*sld + soff + c]);
}
__global__ void convert_split_kernel(const float* __restrict__ s, int sld, int soff,
    u16* __restrict__ dh, u16* __restrict__ dl, int dld, int cols, int total){
    int i = blockIdx.x*256 + threadIdx.x;
    if (i >= total) return;
    int r = i / cols, c = i - r*cols;
    float x = s[(size_t)r*sld + soff + c];
    u16 hi = f2bf(x);
    dh[(size_t)r*dld + c] = hi;
    dl[(size_t)r*dld + c] = f2bf(x - bf2f(hi));
}
__global__ void build_bcq_kernel(const float* __restrict__ fcb, const float* __restrict__ ab1,
    float* __restrict__ d){
    int i = blockIdx.x*256 + threadIdx.x;   // 1280
    if (i < 256) d[i] = fcb[i];
    else if (i < 1280) d[i] = ab1[i - 256];
}
// gather embeddings for a CH-timestep chunk starting at t0: rows (t_local*256+b)
__global__ void gather_chunk_kernel(const int* __restrict__ src, const float* __restrict__ emb,
    u16* __restrict__ xe, int t0){
    int i = blockIdx.x*256 + threadIdx.x;       // CH*256*512
    int m = i >> 9, e = i & 511;
    int tl = m >> 8, b = m & 255;
    int tok = src[b*SS + t0 + tl];
    xe[i] = f2bf(emb[(size_t)tok*EE + e]);
}
__global__ void zero_u16_kernel(u16* p, int n){
    int i = blockIdx.x*256 + threadIdx.x; if (i < n) p[i] = 0;
}
__global__ void zero_f32_kernel(float* p, int n){
    int i = blockIdx.x*256 + threadIdx.x; if (i < n) p[i] = 0.f;
}
__global__ void zero_out0_kernel(float* out0){
    int i = blockIdx.x*256 + threadIdx.x;       // 256*256
    int b = i >> 8, v = i & 255;
    out0[(size_t)b*TT*VV + v] = 0.f;
}
__global__ void dec_init_kernel(const u16* h0f, const u16* h0b, const u16* h1f, const u16* h1b,
    const float* c0f, const float* c0b, const float* c1f, const float* c1b,
    u16* a0h, u16* a0l, u16* a1h, u16* a1l, float* c0, float* c1)
{
    int i = blockIdx.x*256 + threadIdx.x;       // 256*1024
    int m = i >> 10, j = i & 1023;
    u16 h0 = (j < 512) ? h0f[m*512 + j] : h0b[m*512 + j - 512];
    u16 h1 = (j < 512) ? h1f[m*512 + j] : h1b[m*512 + j - 512];
    float cc0 = (j < 512) ? c0f[m*512 + j] : c0b[m*512 + j - 512];
    float cc1 = (j < 512) ? c1f[m*512 + j] : c1b[m*512 + j - 512];
    a0h[(size_t)m*2560 + 1536 + j] = h0; a0l[(size_t)m*2560 + 1536 + j] = 0;
    a1h[(size_t)m*2048 + 1024 + j] = h1; a1l[(size_t)m*2048 + 1024 + j] = 0;
    c0[i] = cc0; c1[i] = cc1;
}

// ---------------- host ----------------
extern "C" void kernel_launch(void* const* d_in, const int* in_sizes, int n_in,
                              void* d_out, int out_size, void* d_ws, size_t ws_size,
                              hipStream_t stream)
{
    (void)in_sizes; (void)n_in; (void)out_size;
    const size_t NEED = 230100000;   // footprint ~222 MB + slack (ws_size >= this, verified R3)
    if (ws_size < NEED) return;

    const int*   src = (const int*)d_in[0];
    const int*   tgt = (const int*)d_in[1];
    const float* enc_embed = (const float*)d_in[2];
    const float* dec_embed = (const float*)d_in[3];
    const float* ew[4][3] = {
        {(const float*)d_in[4],  (const float*)d_in[5],  (const float*)d_in[6]},
        {(const float*)d_in[7],  (const float*)d_in[8],  (const float*)d_in[9]},
        {(const float*)d_in[10], (const float*)d_in[11], (const float*)d_in[12]},
        {(const float*)d_in[13], (const float*)d_in[14], (const float*)d_in[15]},
    };
    const float* d0_wih = (const float*)d_in[16];
    const float* d0_whh = (const float*)d_in[17];
    const float* d0_b   = (const float*)d_in[18];
    const float* d1_wih = (const float*)d_in[19];
    const float* d1_whh = (const float*)d_in[20];
    const float* d1_b   = (const float*)d_in[21];
    const float* attn_w1 = (const float*)d_in[22];
    const float* attn_b1 = (const float*)d_in[23];
    const float* attn_w2 = (const float*)d_in[24];
    const float* attn_b2 = (const float*)d_in[25];
    const float* fc_w = (const float*)d_in[26];
    const float* fc_b = (const float*)d_in[27];

    float* out0 = (float*)d_out;
    float* out1 = out0 + (size_t)BB*TT*VV;

    char* base = (char*)d_ws;
    size_t off = 0;
    auto alloc = [&](size_t nbytes)->char*{
        char* p = base + off;
        off += (nbytes + 255) & ~(size_t)255;
        return p;
    };
    // ---- small persistent ----
    float* b_e[4];
    for (int d2=0; d2<4; d2++) b_e[d2] = (float*)alloc(2048*4);
    float* b0p = (float*)alloc(4096*4);
    float* b1p = (float*)alloc(4096*4);
    float* bcq = (float*)alloc(1280*4);
    u16* hbuf    = (u16*)alloc((size_t)8*256*512*2);      // [dir*2+parity]
    float* cbuf  = (float*)alloc((size_t)4*256*512*4);    // [dir]
    u16* bufA0h = (u16*)alloc((size_t)2*256*2560*2);
    u16* bufA0l = (u16*)alloc((size_t)2*256*2560*2);
    u16* bufA1h = (u16*)alloc((size_t)2*256*2048*2);
    u16* bufA1l = (u16*)alloc((size_t)2*256*2048*2);
    float* c0 = (float*)alloc((size_t)256*1024*4);
    float* c1 = (float*)alloc((size_t)256*1024*4);
    float* qp = (float*)alloc((size_t)256*1024*4);
    float* qdump = (float*)alloc((size_t)256*256*4);      // dummy fc dest for pre-loop combined
    // ---- big persistent ----
    u16* enc_out = (u16*)alloc((size_t)32768*1024*2);     // alive through decoder
    u16* x1      = (u16*)alloc((size_t)32768*1024*2);     // overlay: x1 -> enc_prj
    u16* enc_prj = x1;
    // ---- time-shared region D: encoder scratch (44 MB) THEN decoder weights (81 MB) ----
    char* D = alloc(81000000);
    size_t doff = 0;
    auto carve = [&](size_t nbytes)->char*{ char* p = D + doff; doff += nbytes; return p; };
    const int in_dim_e[4] = {512,512,1024,1024};
    u16* wih_e[4]; u16* whh_e[4];
    for (int d2=0; d2<4; d2++){
        wih_e[d2] = (u16*)carve((size_t)2048*in_dim_e[d2]*2);
        whh_e[d2] = (u16*)carve((size_t)2048*512*2);
    }
    u16* w1enc = (u16*)carve((size_t)1024*1024*2);
    u16* xef   = (u16*)carve((size_t)CH*256*512*2);
    u16* xeb   = (u16*)carve((size_t)CH*256*512*2);
    u16* preA  = (u16*)carve((size_t)CH*256*2048*2);
    u16* preB  = (u16*)carve((size_t)CH*256*2048*2);
    // decoder-phase carve (reuses D from offset 0 — written only after encoder done)
    doff = 0;
    u16* W0h = (u16*)carve((size_t)4096*2560*2);
    u16* W0l = (u16*)carve((size_t)4096*2560*2);
    u16* W1h = (u16*)carve((size_t)4096*2048*2);
    u16* W1l = (u16*)carve((size_t)4096*2048*2);
    u16* Wch = (u16*)carve((size_t)1280*1024*2);          // [fc ; w1q] combined, hi
    u16* Wcl = (u16*)carve((size_t)1280*1024*2);          // lo

    const size_t HSZ2 = 256*512;   // hbuf slot elems
    const size_t CSZ  = 256*512;   // cbuf slot elems
    const size_t A0SZ = 256*2560, A1SZ = 256*2048;

    // ---- encoder weight prep ----
    for (int d2=0; d2<4; d2++){
        int tot = 2048*in_dim_e[d2];
        permute_convert_kernel<<<(tot+255)/256,256,0,stream>>>(ew[d2][0], wih_e[d2], 512, in_dim_e[d2], in_dim_e[d2], 0, tot);
        tot = 2048*512;
        permute_convert_kernel<<<(tot+255)/256,256,0,stream>>>(ew[d2][1], whh_e[d2], 512, 512, 512, 0, tot);
        permute_bias_kernel<<<8,256,0,stream>>>(ew[d2][2], b_e[d2], 512);
    }
    {
        int tw = 1024*1024;
        convert_kernel<<<(tw+255)/256,256,0,stream>>>(attn_w1, 2048, 0, w1enc, 1024, 1024, tw);
    }
    for (int d2=0; d2<4; d2++)
        zero_u16_kernel<<<512,256,0,stream>>>(hbuf + (size_t)(d2*2)*HSZ2, (int)HSZ2);
    zero_f32_kernel<<<2048,256,0,stream>>>(cbuf, 4*(int)CSZ);
    zero_out0_kernel<<<256,256,0,stream>>>(out0);

    // ---- encoder: chunked pre-GEMMs interleaved with scan ----
    for (int layer = 0; layer < 2; layer++){
        const long ldx  = layer ? 1024 : 512;
        const int  dirf = layer*2, dirb = layer*2 + 1;
        for (int c = 0; c < 128/CH; c++){
            const int tf0 = c*CH, tb0 = 128 - CH*(c+1);
            const u16 *Af, *Ab;
            if (layer == 0){
                gather_chunk_kernel<<<CH*512,256,0,stream>>>(src, enc_embed, xef, tf0);
                gather_chunk_kernel<<<CH*512,256,0,stream>>>(src, enc_embed, xeb, tb0);
                Af = xef; Ab = xeb;
            } else {
                Af = x1 + (size_t)tf0*256*1024;
                Ab = x1 + (size_t)tb0*256*1024;
            }
            {
                GArgs a{}, b{};
                a.A = Af; a.lda = ldx; a.Bw = wih_e[dirf]; a.K = ldx; a.bias = b_e[dirf];
                a.Cb = preA; a.ldc = 2048;
                b.A = Ab; b.lda = ldx; b.Bw = wih_e[dirb]; b.K = ldx; b.bias = b_e[dirb];
                b.Cb = preB; b.ldc = 2048;
                gemm2_kernel<2,2><<<dim3(16, CH*2, 2),256,0,stream>>>(a, b);
            }
            for (int i = 0; i < CH; i++){
                int t = c*CH + i;
                GArgs f{}, bq{};
                f.A = hbuf + (size_t)(dirf*2 + (t&1))*HSZ2; f.lda = 512;
                f.Bw = whh_e[dirf]; f.K = 512;
                f.pre = preA + (size_t)i*256*2048; f.ldpre = 2048;
                f.cst = cbuf + (size_t)dirf*CSZ; f.hid = 512;
                if (layer == 0){ f.h1 = x1 + (size_t)t*256*1024;      f.ldh1 = 1024; }
                else           { f.h1 = enc_out + (size_t)t*1024;     f.ldh1 = (long)SS*1024; }
                f.h2 = hbuf + (size_t)(dirf*2 + ((t+1)&1))*HSZ2; f.ldh2 = 512;
                bq = f;
                bq.A = hbuf + (size_t)(dirb*2 + (t&1))*HSZ2;
                bq.Bw = whh_e[dirb];
                bq.pre = preB + (size_t)(CH-1-i)*256*2048;
                bq.cst = cbuf + (size_t)dirb*CSZ;
                if (layer == 0){ bq.h1 = x1 + (size_t)(127-t)*256*1024 + 512; }
                else           { bq.h1 = enc_out + (size_t)(127-t)*1024 + 512; }
                bq.h2 = hbuf + (size_t)(dirb*2 + ((t+1)&1))*HSZ2;
                lstm_step2_kernel<1,2><<<dim3(16,4,2),128,0,stream>>>(f,bq);
            }
        }
    }
    // ---- enc_proj = enc_out @ w1_enc^T  (overwrites x1 region; x1 dead) ----
    {
        GArgs a{}; a.A = enc_out; a.lda = 1024; a.Bw = w1enc; a.K = 1024;
        a.Cb = enc_prj; a.ldc = 1024;
        gemm_kernel<2,2,0,0><<<dim3(8,256),256,0,stream>>>(a);
    }
    // ---- decoder weight prep (region D reuse — encoder scratch now dead) ----
    {
        int tot = 4096*1536;
        permute_convert_split_kernel<<<(tot+255)/256,256,0,stream>>>(d0_wih, W0h, W0l, 1024, 1536, 2560, 0, tot);
        tot = 4096*1024;
        permute_convert_split_kernel<<<(tot+255)/256,256,0,stream>>>(d0_whh, W0h, W0l, 1024, 1024, 2560, 1536, tot);
        permute_bias_kernel<<<16,256,0,stream>>>(d0_b, b0p, 1024);
        tot = 4096*1024;
        permute_convert_split_kernel<<<(tot+255)/256,256,0,stream>>>(d1_wih, W1h, W1l, 1024, 1024, 2048, 0, tot);
        permute_convert_split_kernel<<<(tot+255)/256,256,0,stream>>>(d1_whh, W1h, W1l, 1024, 1024, 2048, 1024, tot);
        permute_bias_kernel<<<16,256,0,stream>>>(d1_b, b1p, 1024);
        // combined [fc ; w1q]
        int tf = 256*1024;
        convert_split_kernel<<<(tf+255)/256,256,0,stream>>>(fc_w, 1024, 0, Wch, Wcl, 1024, 1024, tf);
        int tq = 1024*1024;
        convert_split_kernel<<<(tq+255)/256,256,0,stream>>>(attn_w1, 2048, 1024,
            Wch + (size_t)256*1024, Wcl + (size_t)256*1024, 1024, 1024, tq);
        build_bcq_kernel<<<5,256,0,stream>>>(fc_b, attn_b1, bcq);
    }
    // ---- decoder init ----
    dec_init_kernel<<<1024,256,0,stream>>>(
        hbuf + 0*2*HSZ2, hbuf + 1*2*HSZ2, hbuf + 2*2*HSZ2, hbuf + 3*2*HSZ2,
        cbuf + 0*CSZ, cbuf + 1*CSZ, cbuf + 2*CSZ, cbuf + 3*CSZ,
        bufA0h, bufA0l, bufA1h, bufA1l, c0, c1);

    // initial combined: qp from initial h1 (fc part -> qdump)
    {
        GArgs a{};
        a.A = bufA1h + 1024; a.A2 = bufA1l + 1024; a.lda = 2048;
        a.Bw = Wch; a.B2 = Wcl; a.K = 1024; a.bias = bcq;
        a.Cf = qdump; a.ldc = 256;
        a.cst = qp; a.hid = 1024;
        gemm_kernel<1,2,3,1><<<dim3(10,4),128,0,stream>>>(a);
    }

    // ---- decoder loop: 4 kernels/step ----
    for (int n = 0; n < 127; n++){
        int pc = n & 1, pn = (n+1) & 1;
        attn_kernel<<<256,256,0,stream>>>(enc_prj, enc_out, qp, attn_w2, attn_b2,
            src, tgt, dec_embed, out1,
            bufA0h + (size_t)pc*A0SZ, bufA0l + (size_t)pc*A0SZ, n);
        // dec l0 (split bf16)
        {
            GArgs a{};
            a.A = bufA0h + (size_t)pc*A0SZ; a.A2 = bufA0l + (size_t)pc*A0SZ; a.lda = 2560;
            a.Bw = W0h; a.B2 = W0l; a.K = 2560; a.bias = b0p;
            a.cst = c0; a.hid = 1024;
            a.h1 = bufA0h + (size_t)pn*A0SZ + 1536; a.h1l = bufA0l + (size_t)pn*A0SZ + 1536; a.ldh1 = 2560;
            a.h2 = bufA1h + (size_t)pc*A1SZ;        a.h2l = bufA1l + (size_t)pc*A1SZ;        a.ldh2 = 2048;
            gemm_kernel<1,2,2,1><<<dim3(32,4),128,0,stream>>>(a);
        }
        // dec l1 (split bf16)
        {
            GArgs a{};
            a.A = bufA1h + (size_t)pc*A1SZ; a.A2 = bufA1l + (size_t)pc*A1SZ; a.lda = 2048;
            a.Bw = W1h; a.B2 = W1l; a.K = 2048; a.bias = b1p;
            a.cst = c1; a.hid = 1024;
            a.h1 = bufA1h + (size_t)pn*A1SZ + 1024; a.h1l = bufA1l + (size_t)pn*A1SZ + 1024; a.ldh1 = 2048;
            gemm_kernel<1,2,2,1><<<dim3(32,4),128,0,stream>>>(a);
        }
        // combined: logits -> out0[:, n+1, :]  AND  q_proj(next) -> qp
        {
            GArgs a{};
            a.A = bufA1h + (size_t)pn*A1SZ + 1024; a.A2 = bufA1l + (size_t)pn*A1SZ + 1024; a.lda = 2048;
            a.Bw = Wch; a.B2 = Wcl; a.K = 1024; a.bias = bcq;
            a.Cf = out0 + (size_t)(n+1)*VV; a.ldc = (size_t)TT*VV;
            a.cst = qp; a.hid = 1024;
            gemm_kernel<1,2,3,1><<<dim3(10,4),128,0,stream>>>(a);
        }
    }
}

// Round 5
// 80266.138 us; speedup vs baseline: 1.1849x; 1.1849x over previous
//
#include <hip/hip_runtime.h>
#include <stdint.h>

typedef unsigned short u16;
typedef __attribute__((ext_vector_type(8))) short short8;
typedef __attribute__((ext_vector_type(4))) float f32x4;

#define BB 256
#define SS 128
#define TT 128
#define EE 512
#define HH 1024
#define VV 256

#define BK 64
#define LDSP 72   // padded LDS row length in bf16 elems (144 B = 9*16, keeps 16B alignment)
#define CH 8      // encoder pre-GEMM chunk (timesteps)

__device__ __forceinline__ float bf2f(u16 u){
    union { unsigned int i; float f; } v; v.i = ((unsigned int)u) << 16; return v.f;
}
__device__ __forceinline__ u16 f2bf(float f){
    union { float f; unsigned int i; } v; v.f = f;
    return (u16)((v.i + 0x7fffu + ((v.i >> 16) & 1u)) >> 16);
}
__device__ __forceinline__ float rcp_(float x){ return __builtin_amdgcn_rcpf(x); }
__device__ __forceinline__ float sigm_(float x){ return rcp_(1.f + __expf(-x)); }
__device__ __forceinline__ float tanh_(float x){ return 1.f - 2.f*rcp_(__expf(2.f*x) + 1.f); }

struct GArgs {
    const u16* A;  const u16* A2; long lda;     // A (M,K) bf16 hi / lo
    const u16* Bw; const u16* B2; long K;       // B (N,K) bf16 hi / lo, ldb == K
    const float* bias;                          // len N (indexed by col), nullable
    u16* Cb; float* Cf; long ldc;               // stores
    const u16* pre; long ldpre;                 // LSTM: add pre[row,col], nullable
    float* cst; long hid;                       // LSTM: c state (M, hid) f32
    u16* h1; u16* h1l; long ldh1;               // LSTM: h dest (+lo if split)
    u16* h2; u16* h2l; long ldh2;               // LSTM: optional 2nd h dest
};

// ===== R3-proven GEMM core (NO register prefetch — R4's prefetch spilled VGPRs) =====
// MODE: 0 = store bf16, 1 = store f32, 2 = fused LSTM cell (gate-interleaved cols)
template<int BMW, int BNW, int MODE, int SPLIT>
__device__ __forceinline__ void gemm_core(const GArgs& g)
{
    constexpr int BM = BMW*64, BN = BNW*64;
    constexpr int NT = BMW*BNW*64;
    constexpr int AE = BM*LDSP, BE = BN*LDSP;
    static_assert((BM*8) % NT == 0 && (BN*8) % NT == 0, "staging");
    __shared__ __align__(16) u16 sA[(SPLIT+1)*AE];
    __shared__ __align__(16) u16 sB[(SPLIT+1)*BE];
    const int tid = threadIdx.x;
    const int lane = tid & 63, wave = tid >> 6;
    const int wn = wave % BNW, wm = wave / BNW;
    const int l15 = lane & 15, quad = lane >> 4;
    const long m0 = (long)blockIdx.y * BM, n0 = (long)blockIdx.x * BN;

    f32x4 acc[4][4];
    #pragma unroll
    for (int a=0;a<4;a++)
    #pragma unroll
    for (int c=0;c<4;c++){ f32x4 z = {0.f,0.f,0.f,0.f}; acc[a][c] = z; }

    for (long k0 = 0; k0 < g.K; k0 += BK){
        #pragma unroll
        for (int i = 0; i < BM*8/NT; i++){
            int c = tid + i*NT;
            int r = c >> 3, c8 = (c & 7) * 8;
            *(int4*)&sA[r*LDSP + c8] = *(const int4*)(g.A + (m0 + r)*g.lda + k0 + c8);
            if (SPLIT)
                *(int4*)&sA[AE + r*LDSP + c8] = *(const int4*)(g.A2 + (m0 + r)*g.lda + k0 + c8);
        }
        #pragma unroll
        for (int i = 0; i < BN*8/NT; i++){
            int c = tid + i*NT;
            int r = c >> 3, c8 = (c & 7) * 8;
            *(int4*)&sB[r*LDSP + c8] = *(const int4*)(g.Bw + (n0 + r)*g.K + k0 + c8);
            if (SPLIT)
                *(int4*)&sB[BE + r*LDSP + c8] = *(const int4*)(g.B2 + (n0 + r)*g.K + k0 + c8);
        }
        __syncthreads();
        #pragma unroll
        for (int ks = 0; ks < 2; ks++){
            const int ko = ks*32 + quad*8;
            short8 ah[4], bh[4], al[4], bl[4];
            #pragma unroll
            for (int mi=0; mi<4; mi++){
                int ra = (wm*64 + mi*16 + l15)*LDSP + ko;
                ah[mi] = *(const short8*)&sA[ra];
                if (SPLIT) al[mi] = *(const short8*)&sA[AE + ra];
            }
            #pragma unroll
            for (int ni=0; ni<4; ni++){
                int rb = (wn*64 + ni*16 + l15)*LDSP + ko;
                bh[ni] = *(const short8*)&sB[rb];
                if (SPLIT) bl[ni] = *(const short8*)&sB[BE + rb];
            }
            #pragma unroll
            for (int mi=0; mi<4; mi++)
            #pragma unroll
            for (int ni=0; ni<4; ni++){
                acc[mi][ni] = __builtin_amdgcn_mfma_f32_16x16x32_bf16(ah[mi], bh[ni], acc[mi][ni], 0,0,0);
                if (SPLIT){
                    acc[mi][ni] = __builtin_amdgcn_mfma_f32_16x16x32_bf16(al[mi], bh[ni], acc[mi][ni], 0,0,0);
                    acc[mi][ni] = __builtin_amdgcn_mfma_f32_16x16x32_bf16(ah[mi], bl[ni], acc[mi][ni], 0,0,0);
                }
            }
        }
        __syncthreads();
    }

    // epilogue: C/D layout col = lane&15, row = quad*4 + reg  [m89-verified]
    #pragma unroll
    for (int mi=0; mi<4; mi++)
    #pragma unroll
    for (int ni=0; ni<4; ni++)
    #pragma unroll
    for (int r=0; r<4; r++){
        long row = m0 + wm*64 + mi*16 + quad*4 + r;
        long col = n0 + wn*64 + ni*16 + l15;
        float v = acc[mi][ni][r];
        if (g.bias) v += g.bias[col];
        if (MODE == 2){
            if (g.pre) v += bf2f(g.pre[row*g.ldpre + col]);
            float gf = __shfl_xor(v, 1);
            float gg = __shfl_xor(v, 2);
            float go = __shfl_xor(v, 3);
            if ((lane & 3) == 0){
                long j = col >> 2;
                float co = g.cst[row*g.hid + j];
                float cn = sigm_(gf)*co + sigm_(v)*tanh_(gg);
                g.cst[row*g.hid + j] = cn;
                float hn = sigm_(go)*tanh_(cn);
                u16 hb = f2bf(hn);
                u16 lb = 0;
                if (SPLIT) lb = f2bf(hn - bf2f(hb));
                g.h1[row*g.ldh1 + j] = hb;
                if (SPLIT) g.h1l[row*g.ldh1 + j] = lb;
                if (g.h2){
                    g.h2[row*g.ldh2 + j] = hb;
                    if (SPLIT) g.h2l[row*g.ldh2 + j] = lb;
                }
            }
        } else if (MODE == 1){
            g.Cf[row*g.ldc + col] = v;
        } else {
            g.Cb[row*g.ldc + col] = f2bf(v);
        }
    }
}

template<int BMW,int BNW,int MODE,int SPLIT>
__global__ __launch_bounds__(BMW*BNW*64)
void gemm_kernel(GArgs g){ gemm_core<BMW,BNW,MODE,SPLIT>(g); }

template<int BMW,int BNW>
__global__ __launch_bounds__(BMW*BNW*64)
void lstm_step2_kernel(GArgs gf, GArgs gb){
    if (blockIdx.z == 0) gemm_core<BMW,BNW,2,0>(gf);
    else                 gemm_core<BMW,BNW,2,0>(gb);
}
template<int BMW,int BNW>
__global__ __launch_bounds__(BMW*BNW*64)
void gemm2_kernel(GArgs ga, GArgs gb){
    if (blockIdx.z == 0) gemm_core<BMW,BNW,0,0>(ga);
    else                 gemm_core<BMW,BNW,0,0>(gb);
}

// ==================== decoder megakernel ====================
struct DecArgs {
    const u16* enc_prj; const u16* enc_out;
    const float* w2; const float* b2p;
    const int* src; const int* tgt;
    const float* dec_embed;
    float* out0; float* out1;
    u16 *A0h, *A0l, *A1h, *A1l;     // ping-pong bases
    float *c0, *c1, *qp, *qdump;
    const u16 *W0h,*W0l,*W1h,*W1l,*Wch,*Wcl;
    const float *b0p,*b1p,*bcq;
    unsigned* bar;                  // [0]=cnt,[1]=gen,[2]=dead
};

// device-scope grid barrier (generation-based; AGENT-scope atomics emit the
// cross-XCD wb/inv cache ops per the HIP memory model). Timeout -> dead flag
// so a residency failure degrades to wrong-answer instead of a hang.
__device__ __forceinline__ void gridbar(unsigned* bar)
{
    __threadfence();
    __syncthreads();
    if (threadIdx.x == 0){
        if (__hip_atomic_load(&bar[2], __ATOMIC_RELAXED, __HIP_MEMORY_SCOPE_AGENT) == 0u){
            unsigned g = __hip_atomic_load(&bar[1], __ATOMIC_ACQUIRE, __HIP_MEMORY_SCOPE_AGENT);
            unsigned a = __hip_atomic_fetch_add(&bar[0], 1u, __ATOMIC_ACQ_REL, __HIP_MEMORY_SCOPE_AGENT);
            if (a == gridDim.x - 1u){
                __hip_atomic_store(&bar[0], 0u, __ATOMIC_RELAXED, __HIP_MEMORY_SCOPE_AGENT);
                __hip_atomic_store(&bar[1], g + 1u, __ATOMIC_RELEASE, __HIP_MEMORY_SCOPE_AGENT);
            } else {
                long long t0 = clock64();
                while (__hip_atomic_load(&bar[1], __ATOMIC_ACQUIRE, __HIP_MEMORY_SCOPE_AGENT) == g){
                    __builtin_amdgcn_s_sleep(2);
                    if (clock64() - t0 > 200000000LL){
                        __hip_atomic_store(&bar[2], 1u, __ATOMIC_RELAXED, __HIP_MEMORY_SCOPE_AGENT);
                        break;
                    }
                }
            }
        }
    }
    __syncthreads();
}

// split-bf16 GEMM phase inside megakernel. Block tile 64x64, 4 waves as 2x2 of
// 32x32 wave tiles. nblk = N/64 col-blocks; grid rows = M/64 = 4.
// EPI: 0 = LSTM cell epilogue, 1 = dual f32 (col<256 -> Cf, else -> qp)
template<int EPI>
__device__ void dec_gemm(const u16* Ah, const u16* Al, long lda,
                         const u16* Bh, const u16* Bl, long K,
                         const float* bias,
                         float* cst, u16* h1, u16* h1l, long ldh1,
                         u16* h2, u16* h2l, long ldh2,
                         float* Cf, long ldc, float* qp,
                         int nblk, u16* smem)
{
    const int bid = blockIdx.x;
    if (bid >= nblk * 4) return;
    const int by = bid / nblk, bx = bid - by*nblk;
    const long m0 = (long)by*64, n0 = (long)bx*64;
    u16* sAh = smem;
    u16* sAl = smem + 64*LDSP;
    u16* sBh = smem + 2*64*LDSP;
    u16* sBl = smem + 3*64*LDSP;
    const int tid = threadIdx.x;
    const int lane = tid & 63, wave = tid >> 6;
    const int wm2 = wave >> 1, wn2 = wave & 1;
    const int l15 = lane & 15, quad = lane >> 4;

    f32x4 acc[2][2];
    #pragma unroll
    for (int a=0;a<2;a++)
    #pragma unroll
    for (int c=0;c<2;c++){ f32x4 z = {0.f,0.f,0.f,0.f}; acc[a][c] = z; }

    for (long k0 = 0; k0 < K; k0 += BK){
        #pragma unroll
        for (int i = 0; i < 2; i++){
            int idx = tid + i*256;          // 512 chunks of 8 u16 per matrix
            int r = idx >> 3, c8 = (idx & 7) * 8;
            *(int4*)&sAh[r*LDSP + c8] = *(const int4*)(Ah + (m0 + r)*lda + k0 + c8);
            *(int4*)&sAl[r*LDSP + c8] = *(const int4*)(Al + (m0 + r)*lda + k0 + c8);
            *(int4*)&sBh[r*LDSP + c8] = *(const int4*)(Bh + (n0 + r)*K + k0 + c8);
            *(int4*)&sBl[r*LDSP + c8] = *(const int4*)(Bl + (n0 + r)*K + k0 + c8);
        }
        __syncthreads();
        #pragma unroll
        for (int ks = 0; ks < 2; ks++){
            const int ko = ks*32 + quad*8;
            short8 ah[2], al[2], bh[2], bl[2];
            #pragma unroll
            for (int mi=0; mi<2; mi++){
                int ra = (wm2*32 + mi*16 + l15)*LDSP + ko;
                ah[mi] = *(const short8*)&sAh[ra];
                al[mi] = *(const short8*)&sAl[ra];
            }
            #pragma unroll
            for (int ni=0; ni<2; ni++){
                int rb = (wn2*32 + ni*16 + l15)*LDSP + ko;
                bh[ni] = *(const short8*)&sBh[rb];
                bl[ni] = *(const short8*)&sBl[rb];
            }
            #pragma unroll
            for (int mi=0; mi<2; mi++)
            #pragma unroll
            for (int ni=0; ni<2; ni++){
                acc[mi][ni] = __builtin_amdgcn_mfma_f32_16x16x32_bf16(ah[mi], bh[ni], acc[mi][ni], 0,0,0);
                acc[mi][ni] = __builtin_amdgcn_mfma_f32_16x16x32_bf16(al[mi], bh[ni], acc[mi][ni], 0,0,0);
                acc[mi][ni] = __builtin_amdgcn_mfma_f32_16x16x32_bf16(ah[mi], bl[ni], acc[mi][ni], 0,0,0);
            }
        }
        __syncthreads();
    }

    #pragma unroll
    for (int mi=0; mi<2; mi++)
    #pragma unroll
    for (int ni=0; ni<2; ni++)
    #pragma unroll
    for (int r=0; r<4; r++){
        long row = m0 + wm2*32 + mi*16 + quad*4 + r;
        long col = n0 + wn2*32 + ni*16 + l15;
        float v = acc[mi][ni][r] + bias[col];
        if (EPI == 0){
            float gf = __shfl_xor(v, 1);
            float gg = __shfl_xor(v, 2);
            float go = __shfl_xor(v, 3);
            if ((lane & 3) == 0){
                long j = col >> 2;
                float co = cst[row*1024 + j];
                float cn = sigm_(gf)*co + sigm_(v)*tanh_(gg);
                cst[row*1024 + j] = cn;
                float hn = sigm_(go)*tanh_(cn);
                u16 hb = f2bf(hn);
                u16 lb = f2bf(hn - bf2f(hb));
                h1[row*ldh1 + j] = hb;  h1l[row*ldh1 + j] = lb;
                if (h2){ h2[row*ldh2 + j] = hb;  h2l[row*ldh2 + j] = lb; }
            }
        } else {
            if (col < 256) Cf[row*ldc + col] = v;
            else           qp[row*1024 + (col - 256)] = v;
        }
    }
}

__device__ void attn_phase(const DecArgs& d, int n, u16* a0h, u16* a0l, u16* smem)
{
    float* sE  = (float*)smem;        // 128 f32
    float* sAs = sE + 128;            // 128 f32
    const int b = blockIdx.x;
    const int tid = threadIdx.x;
    const int lane = tid & 63, wave = tid >> 6;
    float qr[16], wr[16];
    const float* qb = d.qp + (size_t)b*HH;
    #pragma unroll
    for (int j=0;j<8;j++){
        qr[j]   = qb[lane*8 + j];        wr[j]   = d.w2[lane*8 + j];
        qr[8+j] = qb[512 + lane*8 + j];  wr[8+j] = d.w2[512 + lane*8 + j];
    }
    float b2 = d.b2p[0];
    for (int ii=0; ii<32; ii++){
        int s = wave*32 + ii;
        const u16* row = d.enc_prj + ((size_t)b*SS + s)*HH;
        int4 r0 = *(const int4*)(row + lane*8);
        int4 r1 = *(const int4*)(row + 512 + lane*8);
        const u16* u0 = (const u16*)&r0;
        const u16* u1 = (const u16*)&r1;
        float acc = 0.f;
        #pragma unroll
        for (int j=0;j<8;j++) acc += tanh_(bf2f(u0[j]) + qr[j]) * wr[j];
        #pragma unroll
        for (int j=0;j<8;j++) acc += tanh_(bf2f(u1[j]) + qr[8+j]) * wr[8+j];
        #pragma unroll
        for (int off=32; off; off>>=1) acc += __shfl_xor(acc, off);
        if (lane == 0){
            float e = acc + b2;
            if (d.src[b*SS + s] == 0) e = -1e30f;
            sE[s] = e;
        }
    }
    __syncthreads();
    if (wave == 0){
        float v0 = sE[lane], v1 = sE[64 + lane];
        float m = fmaxf(v0, v1);
        #pragma unroll
        for (int off=32; off; off>>=1) m = fmaxf(m, __shfl_xor(m, off));
        float p0 = __expf(v0 - m), p1 = __expf(v1 - m);
        float sum = p0 + p1;
        #pragma unroll
        for (int off=32; off; off>>=1) sum += __shfl_xor(sum, off);
        float inv = 1.f / sum;
        float a0 = p0 * inv, a1 = p1 * inv;
        sAs[lane] = a0; sAs[64+lane] = a1;
        float* op = d.out1 + ((size_t)b*(TT-1) + n)*SS;
        op[lane] = a0; op[64+lane] = a1;
    }
    __syncthreads();
    int c4 = tid*4;
    float av0=0, av1=0, av2=0, av3=0;
    const u16* eb = d.enc_out + (size_t)b*SS*HH + c4;
    for (int s=0; s<SS; s++){
        float as = sAs[s];
        uint2 u = *(const uint2*)(eb + (size_t)s*HH);
        const u16* pu = (const u16*)&u;
        av0 += as * bf2f(pu[0]);
        av1 += as * bf2f(pu[1]);
        av2 += as * bf2f(pu[2]);
        av3 += as * bf2f(pu[3]);
    }
    u16* ch = a0h + (size_t)b*2560 + 512 + c4;
    u16* cl = a0l + (size_t)b*2560 + 512 + c4;
    float av[4] = {av0,av1,av2,av3};
    #pragma unroll
    for (int k=0;k<4;k++){
        u16 hi = f2bf(av[k]); ch[k] = hi; cl[k] = f2bf(av[k] - bf2f(hi));
    }
    int tok = d.tgt[b*TT + n];
    const float* ep = d.dec_embed + (size_t)tok*EE;
    u16* ehp = a0h + (size_t)b*2560;
    u16* elp = a0l + (size_t)b*2560;
    #pragma unroll
    for (int k=0;k<2;k++){
        int e = tid*2 + k;
        float x = ep[e];
        u16 hi = f2bf(x);
        ehp[e] = hi; elp[e] = f2bf(x - bf2f(hi));
    }
    __syncthreads();
}

__global__ __launch_bounds__(256)
void dec_mega(DecArgs d)
{
    __shared__ __align__(16) u16 smem[4*64*LDSP];
    const size_t A0SZ = 256*2560, A1SZ = 256*2048;

    // initial combined: qp from h1(parity 0); logits part -> qdump
    dec_gemm<1>(d.A1h + 1024, d.A1l + 1024, 2048, d.Wch, d.Wcl, 1024, d.bcq,
                nullptr, nullptr, nullptr, 0, nullptr, nullptr, 0,
                d.qdump, 256, d.qp, 20, smem);
    gridbar(d.bar);

    for (int n = 0; n < 127; n++){
        const int pc = n & 1, pn = 1 - pc;
        attn_phase(d, n, d.A0h + (size_t)pc*A0SZ, d.A0l + (size_t)pc*A0SZ, smem);
        gridbar(d.bar);
        // dec l0
        dec_gemm<0>(d.A0h + (size_t)pc*A0SZ, d.A0l + (size_t)pc*A0SZ, 2560,
                    d.W0h, d.W0l, 2560, d.b0p,
                    d.c0,
                    d.A0h + (size_t)pn*A0SZ + 1536, d.A0l + (size_t)pn*A0SZ + 1536, 2560,
                    d.A1h + (size_t)pc*A1SZ,        d.A1l + (size_t)pc*A1SZ,        2048,
                    nullptr, 0, nullptr, 64, smem);
        gridbar(d.bar);
        // dec l1
        dec_gemm<0>(d.A1h + (size_t)pc*A1SZ, d.A1l + (size_t)pc*A1SZ, 2048,
                    d.W1h, d.W1l, 2048, d.b1p,
                    d.c1,
                    d.A1h + (size_t)pn*A1SZ + 1024, d.A1l + (size_t)pn*A1SZ + 1024, 2048,
                    nullptr, nullptr, 0,
                    nullptr, 0, nullptr, 64, smem);
        gridbar(d.bar);
        // combined: logits -> out0[:, n+1, :], q_proj(next) -> qp
        dec_gemm<1>(d.A1h + (size_t)pn*A1SZ + 1024, d.A1l + (size_t)pn*A1SZ + 1024, 2048,
                    d.Wch, d.Wcl, 1024, d.bcq,
                    nullptr, nullptr, nullptr, 0, nullptr, nullptr, 0,
                    d.out0 + (size_t)(n+1)*VV, (long)TT*VV, d.qp, 20, smem);
        gridbar(d.bar);
    }
}

// ---------------- prep / utility kernels ----------------
__global__ void permute_convert_kernel(const float* __restrict__ s, u16* __restrict__ d,
    int hid, int cols, int dld, int doff, int total){
    int i = blockIdx.x*256 + threadIdx.x;
    if (i >= total) return;
    int p = i / cols, c = i - p*cols;
    int j = p >> 2, q = p & 3;
    d[(size_t)p*dld + doff + c] = f2bf(s[((size_t)q*hid + j)*cols + c]);
}
__global__ void permute_convert_split_kernel(const float* __restrict__ s, u16* __restrict__ dh,
    u16* __restrict__ dl, int hid, int cols, int dld, int doff, int total){
    int i = blockIdx.x*256 + threadIdx.x;
    if (i >= total) return;
    int p = i / cols, c = i - p*cols;
    int j = p >> 2, q = p & 3;
    float x = s[((size_t)q*hid + j)*cols + c];
    u16 hi = f2bf(x);
    dh[(size_t)p*dld + doff + c] = hi;
    dl[(size_t)p*dld + doff + c] = f2bf(x - bf2f(hi));
}
__global__ void permute_bias_kernel(const float* __restrict__ s, float* __restrict__ d, int hid){
    int p = blockIdx.x*256 + threadIdx.x;
    if (p >= 4*hid) return;
    int j = p >> 2, q = p & 3;
    d[p] = s[q*hid + j];
}
__global__ void convert_kernel(const float* __restrict__ s, int sld, int soff,
    u16* __restrict__ d, int dld, int cols, int total){
    int i = blockIdx.x*256 + threadIdx.x;
    if (i >= total) return;
    int r = i / cols, c = i - r*cols;
    d[(size_t)r*dld + c] = f2bf(s[(size_t)r*sld + soff + c]);
}
__global__ void convert_split_kernel(const float* __restrict__ s, int sld, int soff,
    u16* __restrict__ dh, u16* __restrict__ dl, int dld, int cols, int total){
    int i = blockIdx.x*256 + threadIdx.x;
    if (i >= total) return;
    int r = i / cols, c = i - r*cols;
    float x = s[(size_t)r*sld + soff + c];
    u16 hi = f2bf(x);
    dh[(size_t)r*dld + c] = hi;
    dl[(size_t)r*dld + c] = f2bf(x - bf2f(hi));
}
__global__ void build_bcq_kernel(const float* __restrict__ fcb, const float* __restrict__ ab1,
    float* __restrict__ d){
    int i = blockIdx.x*256 + threadIdx.x;   // 1280
    if (i < 256) d[i] = fcb[i];
    else if (i < 1280) d[i] = ab1[i - 256];
}
__global__ void gather_chunk_kernel(const int* __restrict__ src, const float* __restrict__ emb,
    u16* __restrict__ xe, int t0){
    int i = blockIdx.x*256 + threadIdx.x;       // CH*256*512
    int m = i >> 9, e = i & 511;
    int tl = m >> 8, b = m & 255;
    int tok = src[b*SS + t0 + tl];
    xe[i] = f2bf(emb[(size_t)tok*EE + e]);
}
__global__ void zero_u16_kernel(u16* p, int n){
    int i = blockIdx.x*256 + threadIdx.x; if (i < n) p[i] = 0;
}
__global__ void zero_f32_kernel(float* p, int n){
    int i = blockIdx.x*256 + threadIdx.x; if (i < n) p[i] = 0.f;
}
__global__ void zero_out0_kernel(float* out0){
    int i = blockIdx.x*256 + threadIdx.x;       // 256*256
    int b = i >> 8, v = i & 255;
    out0[(size_t)b*TT*VV + v] = 0.f;
}
__global__ void zero_bar_kernel(unsigned* b){
    if (threadIdx.x < 8) b[threadIdx.x] = 0u;
}
__global__ void dec_init_kernel(const u16* h0f, const u16* h0b, const u16* h1f, const u16* h1b,
    const float* c0f, const float* c0b, const float* c1f, const float* c1b,
    u16* a0h, u16* a0l, u16* a1h, u16* a1l, float* c0, float* c1)
{
    int i = blockIdx.x*256 + threadIdx.x;       // 256*1024
    int m = i >> 10, j = i & 1023;
    u16 h0 = (j < 512) ? h0f[m*512 + j] : h0b[m*512 + j - 512];
    u16 h1 = (j < 512) ? h1f[m*512 + j] : h1b[m*512 + j - 512];
    float cc0 = (j < 512) ? c0f[m*512 + j] : c0b[m*512 + j - 512];
    float cc1 = (j < 512) ? c1f[m*512 + j] : c1b[m*512 + j - 512];
    a0h[(size_t)m*2560 + 1536 + j] = h0; a0l[(size_t)m*2560 + 1536 + j] = 0;
    a1h[(size_t)m*2048 + 1024 + j] = h1; a1l[(size_t)m*2048 + 1024 + j] = 0;
    c0[i] = cc0; c1[i] = cc1;
}

// ---------------- host ----------------
extern "C" void kernel_launch(void* const* d_in, const int* in_sizes, int n_in,
                              void* d_out, int out_size, void* d_ws, size_t ws_size,
                              hipStream_t stream)
{
    (void)in_sizes; (void)n_in; (void)out_size;
    const size_t NEED = 230100000;
    if (ws_size < NEED) return;

    const int*   src = (const int*)d_in[0];
    const int*   tgt = (const int*)d_in[1];
    const float* enc_embed = (const float*)d_in[2];
    const float* dec_embed = (const float*)d_in[3];
    const float* ew[4][3] = {
        {(const float*)d_in[4],  (const float*)d_in[5],  (const float*)d_in[6]},
        {(const float*)d_in[7],  (const float*)d_in[8],  (const float*)d_in[9]},
        {(const float*)d_in[10], (const float*)d_in[11], (const float*)d_in[12]},
        {(const float*)d_in[13], (const float*)d_in[14], (const float*)d_in[15]},
    };
    const float* d0_wih = (const float*)d_in[16];
    const float* d0_whh = (const float*)d_in[17];
    const float* d0_b   = (const float*)d_in[18];
    const float* d1_wih = (const float*)d_in[19];
    const float* d1_whh = (const float*)d_in[20];
    const float* d1_b   = (const float*)d_in[21];
    const float* attn_w1 = (const float*)d_in[22];
    const float* attn_b1 = (const float*)d_in[23];
    const float* attn_w2 = (const float*)d_in[24];
    const float* attn_b2 = (const float*)d_in[25];
    const float* fc_w = (const float*)d_in[26];
    const float* fc_b = (const float*)d_in[27];

    float* out0 = (float*)d_out;
    float* out1 = out0 + (size_t)BB*TT*VV;

    char* base = (char*)d_ws;
    size_t off = 0;
    auto alloc = [&](size_t nbytes)->char*{
        char* p = base + off;
        off += (nbytes + 255) & ~(size_t)255;
        return p;
    };
    float* b_e[4];
    for (int d2=0; d2<4; d2++) b_e[d2] = (float*)alloc(2048*4);
    float* b0p = (float*)alloc(4096*4);
    float* b1p = (float*)alloc(4096*4);
    float* bcq = (float*)alloc(1280*4);
    unsigned* bflags = (unsigned*)alloc(256);
    u16* hbuf    = (u16*)alloc((size_t)8*256*512*2);
    float* cbuf  = (float*)alloc((size_t)4*256*512*4);
    u16* bufA0h = (u16*)alloc((size_t)2*256*2560*2);
    u16* bufA0l = (u16*)alloc((size_t)2*256*2560*2);
    u16* bufA1h = (u16*)alloc((size_t)2*256*2048*2);
    u16* bufA1l = (u16*)alloc((size_t)2*256*2048*2);
    float* c0 = (float*)alloc((size_t)256*1024*4);
    float* c1 = (float*)alloc((size_t)256*1024*4);
    float* qp = (float*)alloc((size_t)256*1024*4);
    float* qdump = (float*)alloc((size_t)256*256*4);
    u16* enc_out = (u16*)alloc((size_t)32768*1024*2);
    u16* x1      = (u16*)alloc((size_t)32768*1024*2);
    u16* enc_prj = x1;
    char* D = alloc(81000000);
    size_t doff = 0;
    auto carve = [&](size_t nbytes)->char*{ char* p = D + doff; doff += nbytes; return p; };
    const int in_dim_e[4] = {512,512,1024,1024};
    u16* wih_e[4]; u16* whh_e[4];
    for (int d2=0; d2<4; d2++){
        wih_e[d2] = (u16*)carve((size_t)2048*in_dim_e[d2]*2);
        whh_e[d2] = (u16*)carve((size_t)2048*512*2);
    }
    u16* w1enc = (u16*)carve((size_t)1024*1024*2);
    u16* xef   = (u16*)carve((size_t)CH*256*512*2);
    u16* xeb   = (u16*)carve((size_t)CH*256*512*2);
    u16* preA  = (u16*)carve((size_t)CH*256*2048*2);
    u16* preB  = (u16*)carve((size_t)CH*256*2048*2);
    doff = 0;
    u16* W0h = (u16*)carve((size_t)4096*2560*2);
    u16* W0l = (u16*)carve((size_t)4096*2560*2);
    u16* W1h = (u16*)carve((size_t)4096*2048*2);
    u16* W1l = (u16*)carve((size_t)4096*2048*2);
    u16* Wch = (u16*)carve((size_t)1280*1024*2);
    u16* Wcl = (u16*)carve((size_t)1280*1024*2);

    const size_t HSZ2 = 256*512;
    const size_t CSZ  = 256*512;

    // ---- encoder weight prep ----
    for (int d2=0; d2<4; d2++){
        int tot = 2048*in_dim_e[d2];
        permute_convert_kernel<<<(tot+255)/256,256,0,stream>>>(ew[d2][0], wih_e[d2], 512, in_dim_e[d2], in_dim_e[d2], 0, tot);
        tot = 2048*512;
        permute_convert_kernel<<<(tot+255)/256,256,0,stream>>>(ew[d2][1], whh_e[d2], 512, 512, 512, 0, tot);
        permute_bias_kernel<<<8,256,0,stream>>>(ew[d2][2], b_e[d2], 512);
    }
    {
        int tw = 1024*1024;
        convert_kernel<<<(tw+255)/256,256,0,stream>>>(attn_w1, 2048, 0, w1enc, 1024, 1024, tw);
    }
    for (int d2=0; d2<4; d2++)
        zero_u16_kernel<<<512,256,0,stream>>>(hbuf + (size_t)(d2*2)*HSZ2, (int)HSZ2);
    zero_f32_kernel<<<2048,256,0,stream>>>(cbuf, 4*(int)CSZ);
    zero_out0_kernel<<<256,256,0,stream>>>(out0);

    // ---- encoder: chunked pre-GEMMs interleaved with scan ----
    for (int layer = 0; layer < 2; layer++){
        const long ldx  = layer ? 1024 : 512;
        const int  dirf = layer*2, dirb = layer*2 + 1;
        for (int c = 0; c < 128/CH; c++){
            const int tf0 = c*CH, tb0 = 128 - CH*(c+1);
            const u16 *Af, *Ab;
            if (layer == 0){
                gather_chunk_kernel<<<CH*512,256,0,stream>>>(src, enc_embed, xef, tf0);
                gather_chunk_kernel<<<CH*512,256,0,stream>>>(src, enc_embed, xeb, tb0);
                Af = xef; Ab = xeb;
            } else {
                Af = x1 + (size_t)tf0*256*1024;
                Ab = x1 + (size_t)tb0*256*1024;
            }
            {
                GArgs a{}, b{};
                a.A = Af; a.lda = ldx; a.Bw = wih_e[dirf]; a.K = ldx; a.bias = b_e[dirf];
                a.Cb = preA; a.ldc = 2048;
                b.A = Ab; b.lda = ldx; b.Bw = wih_e[dirb]; b.K = ldx; b.bias = b_e[dirb];
                b.Cb = preB; b.ldc = 2048;
                gemm2_kernel<2,2><<<dim3(16, CH*2, 2),256,0,stream>>>(a, b);
            }
            for (int i = 0; i < CH; i++){
                int t = c*CH + i;
                GArgs f{}, bq{};
                f.A = hbuf + (size_t)(dirf*2 + (t&1))*HSZ2; f.lda = 512;
                f.Bw = whh_e[dirf]; f.K = 512;
                f.pre = preA + (size_t)i*256*2048; f.ldpre = 2048;
                f.cst = cbuf + (size_t)dirf*CSZ; f.hid = 512;
                if (layer == 0){ f.h1 = x1 + (size_t)t*256*1024;      f.ldh1 = 1024; }
                else           { f.h1 = enc_out + (size_t)t*1024;     f.ldh1 = (long)SS*1024; }
                f.h2 = hbuf + (size_t)(dirf*2 + ((t+1)&1))*HSZ2; f.ldh2 = 512;
                bq = f;
                bq.A = hbuf + (size_t)(dirb*2 + (t&1))*HSZ2;
                bq.Bw = whh_e[dirb];
                bq.pre = preB + (size_t)(CH-1-i)*256*2048;
                bq.cst = cbuf + (size_t)dirb*CSZ;
                if (layer == 0){ bq.h1 = x1 + (size_t)(127-t)*256*1024 + 512; }
                else           { bq.h1 = enc_out + (size_t)(127-t)*1024 + 512; }
                bq.h2 = hbuf + (size_t)(dirb*2 + ((t+1)&1))*HSZ2;
                lstm_step2_kernel<1,2><<<dim3(16,4,2),128,0,stream>>>(f,bq);
            }
        }
    }
    // ---- enc_proj = enc_out @ w1_enc^T ----
    {
        GArgs a{}; a.A = enc_out; a.lda = 1024; a.Bw = w1enc; a.K = 1024;
        a.Cb = enc_prj; a.ldc = 1024;
        gemm_kernel<2,2,0,0><<<dim3(8,256),256,0,stream>>>(a);
    }
    // ---- decoder weight prep ----
    {
        int tot = 4096*1536;
        permute_convert_split_kernel<<<(tot+255)/256,256,0,stream>>>(d0_wih, W0h, W0l, 1024, 1536, 2560, 0, tot);
        tot = 4096*1024;
        permute_convert_split_kernel<<<(tot+255)/256,256,0,stream>>>(d0_whh, W0h, W0l, 1024, 1024, 2560, 1536, tot);
        permute_bias_kernel<<<16,256,0,stream>>>(d0_b, b0p, 1024);
        tot = 4096*1024;
        permute_convert_split_kernel<<<(tot+255)/256,256,0,stream>>>(d1_wih, W1h, W1l, 1024, 1024, 2048, 0, tot);
        permute_convert_split_kernel<<<(tot+255)/256,256,0,stream>>>(d1_whh, W1h, W1l, 1024, 1024, 2048, 1024, tot);
        permute_bias_kernel<<<16,256,0,stream>>>(d1_b, b1p, 1024);
        int tf = 256*1024;
        convert_split_kernel<<<(tf+255)/256,256,0,stream>>>(fc_w, 1024, 0, Wch, Wcl, 1024, 1024, tf);
        int tq = 1024*1024;
        convert_split_kernel<<<(tq+255)/256,256,0,stream>>>(attn_w1, 2048, 1024,
            Wch + (size_t)256*1024, Wcl + (size_t)256*1024, 1024, 1024, tq);
        build_bcq_kernel<<<5,256,0,stream>>>(fc_b, attn_b1, bcq);
    }
    // ---- decoder init + megakernel ----
    dec_init_kernel<<<1024,256,0,stream>>>(
        hbuf + 0*2*HSZ2, hbuf + 1*2*HSZ2, hbuf + 2*2*HSZ2, hbuf + 3*2*HSZ2,
        cbuf + 0*CSZ, cbuf + 1*CSZ, cbuf + 2*CSZ, cbuf + 3*CSZ,
        bufA0h, bufA0l, bufA1h, bufA1l, c0, c1);
    zero_bar_kernel<<<1,64,0,stream>>>(bflags);

    DecArgs da{};
    da.enc_prj = enc_prj; da.enc_out = enc_out;
    da.w2 = attn_w2; da.b2p = attn_b2;
    da.src = src; da.tgt = tgt; da.dec_embed = dec_embed;
    da.out0 = out0; da.out1 = out1;
    da.A0h = bufA0h; da.A0l = bufA0l; da.A1h = bufA1h; da.A1l = bufA1l;
    da.c0 = c0; da.c1 = c1; da.qp = qp; da.qdump = qdump;
    da.W0h = W0h; da.W0l = W0l; da.W1h = W1h; da.W1l = W1l;
    da.Wch = Wch; da.Wcl = Wcl;
    da.b0p = b0p; da.b1p = b1p; da.bcq = bcq;
    da.bar = bflags;
    dec_mega<<<256,256,0,stream>>>(da);
}

// Round 6
// 71964.069 us; speedup vs baseline: 1.3216x; 1.1154x over previous
//
#include <hip/hip_runtime.h>
#include <stdint.h>

typedef unsigned short u16;
typedef __attribute__((ext_vector_type(8))) short short8;
typedef __attribute__((ext_vector_type(4))) float f32x4;

#define BB 256
#define SS 128
#define TT 128
#define EE 512
#define HH 1024
#define VV 256

#define BK 64
#define LDSP 72   // padded LDS row length in bf16 elems (144 B = 9*16, keeps 16B alignment)
#define CH 8      // encoder pre-GEMM chunk (timesteps)

__device__ __forceinline__ float bf2f(u16 u){
    union { unsigned int i; float f; } v; v.i = ((unsigned int)u) << 16; return v.f;
}
__device__ __forceinline__ u16 f2bf(float f){
    union { float f; unsigned int i; } v; v.f = f;
    return (u16)((v.i + 0x7fffu + ((v.i >> 16) & 1u)) >> 16);
}
__device__ __forceinline__ float rcp_(float x){ return __builtin_amdgcn_rcpf(x); }
__device__ __forceinline__ float sigm_(float x){ return rcp_(1.f + __expf(-x)); }
__device__ __forceinline__ float tanh_(float x){ return 1.f - 2.f*rcp_(__expf(2.f*x) + 1.f); }

struct GArgs {
    const u16* A;  const u16* A2; long lda;
    const u16* Bw; const u16* B2; long K;
    const float* bias;
    u16* Cb; float* Cf; long ldc;
    const u16* pre; long ldpre;
    float* cst; long hid;
    u16* h1; u16* h1l; long ldh1;
    u16* h2; u16* h2l; long ldh2;
};

// ===== R3-proven GEMM core (no register prefetch) =====
template<int BMW, int BNW, int MODE, int SPLIT>
__device__ __forceinline__ void gemm_core(const GArgs& g)
{
    constexpr int BM = BMW*64, BN = BNW*64;
    constexpr int NT = BMW*BNW*64;
    constexpr int AE = BM*LDSP, BE = BN*LDSP;
    static_assert((BM*8) % NT == 0 && (BN*8) % NT == 0, "staging");
    __shared__ __align__(16) u16 sA[(SPLIT+1)*AE];
    __shared__ __align__(16) u16 sB[(SPLIT+1)*BE];
    const int tid = threadIdx.x;
    const int lane = tid & 63, wave = tid >> 6;
    const int wn = wave % BNW, wm = wave / BNW;
    const int l15 = lane & 15, quad = lane >> 4;
    const long m0 = (long)blockIdx.y * BM, n0 = (long)blockIdx.x * BN;

    f32x4 acc[4][4];
    #pragma unroll
    for (int a=0;a<4;a++)
    #pragma unroll
    for (int c=0;c<4;c++){ f32x4 z = {0.f,0.f,0.f,0.f}; acc[a][c] = z; }

    for (long k0 = 0; k0 < g.K; k0 += BK){
        #pragma unroll
        for (int i = 0; i < BM*8/NT; i++){
            int c = tid + i*NT;
            int r = c >> 3, c8 = (c & 7) * 8;
            *(int4*)&sA[r*LDSP + c8] = *(const int4*)(g.A + (m0 + r)*g.lda + k0 + c8);
            if (SPLIT)
                *(int4*)&sA[AE + r*LDSP + c8] = *(const int4*)(g.A2 + (m0 + r)*g.lda + k0 + c8);
        }
        #pragma unroll
        for (int i = 0; i < BN*8/NT; i++){
            int c = tid + i*NT;
            int r = c >> 3, c8 = (c & 7) * 8;
            *(int4*)&sB[r*LDSP + c8] = *(const int4*)(g.Bw + (n0 + r)*g.K + k0 + c8);
            if (SPLIT)
                *(int4*)&sB[BE + r*LDSP + c8] = *(const int4*)(g.B2 + (n0 + r)*g.K + k0 + c8);
        }
        __syncthreads();
        #pragma unroll
        for (int ks = 0; ks < 2; ks++){
            const int ko = ks*32 + quad*8;
            short8 ah[4], bh[4], al[4], bl[4];
            #pragma unroll
            for (int mi=0; mi<4; mi++){
                int ra = (wm*64 + mi*16 + l15)*LDSP + ko;
                ah[mi] = *(const short8*)&sA[ra];
                if (SPLIT) al[mi] = *(const short8*)&sA[AE + ra];
            }
            #pragma unroll
            for (int ni=0; ni<4; ni++){
                int rb = (wn*64 + ni*16 + l15)*LDSP + ko;
                bh[ni] = *(const short8*)&sB[rb];
                if (SPLIT) bl[ni] = *(const short8*)&sB[BE + rb];
            }
            #pragma unroll
            for (int mi=0; mi<4; mi++)
            #pragma unroll
            for (int ni=0; ni<4; ni++){
                acc[mi][ni] = __builtin_amdgcn_mfma_f32_16x16x32_bf16(ah[mi], bh[ni], acc[mi][ni], 0,0,0);
                if (SPLIT){
                    acc[mi][ni] = __builtin_amdgcn_mfma_f32_16x16x32_bf16(al[mi], bh[ni], acc[mi][ni], 0,0,0);
                    acc[mi][ni] = __builtin_amdgcn_mfma_f32_16x16x32_bf16(ah[mi], bl[ni], acc[mi][ni], 0,0,0);
                }
            }
        }
        __syncthreads();
    }

    #pragma unroll
    for (int mi=0; mi<4; mi++)
    #pragma unroll
    for (int ni=0; ni<4; ni++)
    #pragma unroll
    for (int r=0; r<4; r++){
        long row = m0 + wm*64 + mi*16 + quad*4 + r;
        long col = n0 + wn*64 + ni*16 + l15;
        float v = acc[mi][ni][r];
        if (g.bias) v += g.bias[col];
        if (MODE == 2){
            if (g.pre) v += bf2f(g.pre[row*g.ldpre + col]);
            float gf = __shfl_xor(v, 1);
            float gg = __shfl_xor(v, 2);
            float go = __shfl_xor(v, 3);
            if ((lane & 3) == 0){
                long j = col >> 2;
                float co = g.cst[row*g.hid + j];
                float cn = sigm_(gf)*co + sigm_(v)*tanh_(gg);
                g.cst[row*g.hid + j] = cn;
                float hn = sigm_(go)*tanh_(cn);
                u16 hb = f2bf(hn);
                u16 lb = 0;
                if (SPLIT) lb = f2bf(hn - bf2f(hb));
                g.h1[row*g.ldh1 + j] = hb;
                if (SPLIT) g.h1l[row*g.ldh1 + j] = lb;
                if (g.h2){
                    g.h2[row*g.ldh2 + j] = hb;
                    if (SPLIT) g.h2l[row*g.ldh2 + j] = lb;
                }
            }
        } else if (MODE == 1){
            g.Cf[row*g.ldc + col] = v;
        } else {
            g.Cb[row*g.ldc + col] = f2bf(v);
        }
    }
}

template<int BMW,int BNW,int MODE,int SPLIT>
__global__ __launch_bounds__(BMW*BNW*64)
void gemm_kernel(GArgs g){ gemm_core<BMW,BNW,MODE,SPLIT>(g); }

template<int BMW,int BNW>
__global__ __launch_bounds__(BMW*BNW*64)
void lstm_step2_kernel(GArgs gf, GArgs gb){
    if (blockIdx.z == 0) gemm_core<BMW,BNW,2,0>(gf);
    else                 gemm_core<BMW,BNW,2,0>(gb);
}
template<int BMW,int BNW>
__global__ __launch_bounds__(BMW*BNW*64)
void gemm2_kernel(GArgs ga, GArgs gb){
    if (blockIdx.z == 0) gemm_core<BMW,BNW,0,0>(ga);
    else                 gemm_core<BMW,BNW,0,0>(gb);
}

// ==================== decoder megakernel ====================
struct DecArgs {
    const u16* enc_prj; const u16* enc_out;
    const float* w2; const float* b2p;
    const int* src; const int* tgt;
    const float* dec_embed;
    float* out0; float* out1;
    u16 *A0h, *A0l, *A1h, *A1l;
    float *c0, *c1, *qp, *qdump;
    const u16 *W0h,*W0l,*W1h,*W1l,*Wch,*Wcl;
    const float *b0p,*b1p,*bcq;
    unsigned* bar;   // [0..255]=per-block arrival flags, [256]=gen, [257]=dead
};

// Flag-array grid barrier. RELAXED polls (no per-poll cache invalidation — the
// R5 ACQUIRE-spin invalidated L2 every ~130cyc chip-wide), no contended RMW.
// Exactly one wb fence before arrival and one inv fence after release.
__device__ __forceinline__ void gridbar(unsigned* bar, unsigned g)
{
    __threadfence();            // wb: this wave's stores -> LLC
    __syncthreads();            // all waves of block flushed
    const int tid = threadIdx.x;
    if (blockIdx.x == 0){
        if (tid >= 1 && tid < 256){
            if (__hip_atomic_load(&bar[257], __ATOMIC_RELAXED, __HIP_MEMORY_SCOPE_AGENT) == 0u){
                long long t0 = clock64();
                while (__hip_atomic_load(&bar[tid], __ATOMIC_RELAXED, __HIP_MEMORY_SCOPE_AGENT) < g){
                    __builtin_amdgcn_s_sleep(1);
                    if (clock64() - t0 > 100000000LL){
                        __hip_atomic_store(&bar[257], 1u, __ATOMIC_RELAXED, __HIP_MEMORY_SCOPE_AGENT);
                        break;
                    }
                }
            }
        }
        __syncthreads();        // all arrivals observed
        if (tid == 0)
            __hip_atomic_store(&bar[256], g, __ATOMIC_RELAXED, __HIP_MEMORY_SCOPE_AGENT);
    } else {
        if (tid == 0){
            __hip_atomic_store(&bar[blockIdx.x], g, __ATOMIC_RELAXED, __HIP_MEMORY_SCOPE_AGENT);
            if (__hip_atomic_load(&bar[257], __ATOMIC_RELAXED, __HIP_MEMORY_SCOPE_AGENT) == 0u){
                long long t0 = clock64();
                while (__hip_atomic_load(&bar[256], __ATOMIC_RELAXED, __HIP_MEMORY_SCOPE_AGENT) < g){
                    __builtin_amdgcn_s_sleep(1);
                    if (clock64() - t0 > 100000000LL){
                        __hip_atomic_store(&bar[257], 1u, __ATOMIC_RELAXED, __HIP_MEMORY_SCOPE_AGENT);
                        break;
                    }
                }
            }
        }
        __syncthreads();        // release observed
    }
    __threadfence();            // inv: read peers' data fresh
    __syncthreads();
}

// split-bf16 GEMM phase inside megakernel. Block tile 64x64, 2x2 waves of 32x32.
template<int EPI>
__device__ void dec_gemm(const u16* Ah, const u16* Al, long lda,
                         const u16* Bh, const u16* Bl, long K,
                         const float* bias,
                         float* cst, u16* h1, u16* h1l, long ldh1,
                         u16* h2, u16* h2l, long ldh2,
                         float* Cf, long ldc, float* qp,
                         int nblk, u16* smem)
{
    const int bid = blockIdx.x;
    if (bid >= nblk * 4) return;
    const int by = bid / nblk, bx = bid - by*nblk;
    const long m0 = (long)by*64, n0 = (long)bx*64;
    u16* sAh = smem;
    u16* sAl = smem + 64*LDSP;
    u16* sBh = smem + 2*64*LDSP;
    u16* sBl = smem + 3*64*LDSP;
    const int tid = threadIdx.x;
    const int lane = tid & 63, wave = tid >> 6;
    const int wm2 = wave >> 1, wn2 = wave & 1;
    const int l15 = lane & 15, quad = lane >> 4;

    f32x4 acc[2][2];
    #pragma unroll
    for (int a=0;a<2;a++)
    #pragma unroll
    for (int c=0;c<2;c++){ f32x4 z = {0.f,0.f,0.f,0.f}; acc[a][c] = z; }

    for (long k0 = 0; k0 < K; k0 += BK){
        #pragma unroll
        for (int i = 0; i < 2; i++){
            int idx = tid + i*256;
            int r = idx >> 3, c8 = (idx & 7) * 8;
            *(int4*)&sAh[r*LDSP + c8] = *(const int4*)(Ah + (m0 + r)*lda + k0 + c8);
            *(int4*)&sAl[r*LDSP + c8] = *(const int4*)(Al + (m0 + r)*lda + k0 + c8);
            *(int4*)&sBh[r*LDSP + c8] = *(const int4*)(Bh + (n0 + r)*K + k0 + c8);
            *(int4*)&sBl[r*LDSP + c8] = *(const int4*)(Bl + (n0 + r)*K + k0 + c8);
        }
        __syncthreads();
        #pragma unroll
        for (int ks = 0; ks < 2; ks++){
            const int ko = ks*32 + quad*8;
            short8 ah[2], al[2], bh[2], bl[2];
            #pragma unroll
            for (int mi=0; mi<2; mi++){
                int ra = (wm2*32 + mi*16 + l15)*LDSP + ko;
                ah[mi] = *(const short8*)&sAh[ra];
                al[mi] = *(const short8*)&sAl[ra];
            }
            #pragma unroll
            for (int ni=0; ni<2; ni++){
                int rb = (wn2*32 + ni*16 + l15)*LDSP + ko;
                bh[ni] = *(const short8*)&sBh[rb];
                bl[ni] = *(const short8*)&sBl[rb];
            }
            #pragma unroll
            for (int mi=0; mi<2; mi++)
            #pragma unroll
            for (int ni=0; ni<2; ni++){
                acc[mi][ni] = __builtin_amdgcn_mfma_f32_16x16x32_bf16(ah[mi], bh[ni], acc[mi][ni], 0,0,0);
                acc[mi][ni] = __builtin_amdgcn_mfma_f32_16x16x32_bf16(al[mi], bh[ni], acc[mi][ni], 0,0,0);
                acc[mi][ni] = __builtin_amdgcn_mfma_f32_16x16x32_bf16(ah[mi], bl[ni], acc[mi][ni], 0,0,0);
            }
        }
        __syncthreads();
    }

    #pragma unroll
    for (int mi=0; mi<2; mi++)
    #pragma unroll
    for (int ni=0; ni<2; ni++)
    #pragma unroll
    for (int r=0; r<4; r++){
        long row = m0 + wm2*32 + mi*16 + quad*4 + r;
        long col = n0 + wn2*32 + ni*16 + l15;
        float v = acc[mi][ni][r] + bias[col];
        if (EPI == 0){
            float gf = __shfl_xor(v, 1);
            float gg = __shfl_xor(v, 2);
            float go = __shfl_xor(v, 3);
            if ((lane & 3) == 0){
                long j = col >> 2;
                float co = cst[row*1024 + j];
                float cn = sigm_(gf)*co + sigm_(v)*tanh_(gg);
                cst[row*1024 + j] = cn;
                float hn = sigm_(go)*tanh_(cn);
                u16 hb = f2bf(hn);
                u16 lb = f2bf(hn - bf2f(hb));
                h1[row*ldh1 + j] = hb;  h1l[row*ldh1 + j] = lb;
                if (h2){ h2[row*ldh2 + j] = hb;  h2l[row*ldh2 + j] = lb; }
            }
        } else {
            if (col < 256) Cf[row*ldc + col] = v;
            else           qp[row*1024 + (col - 256)] = v;
        }
    }
}

__device__ void attn_phase(const DecArgs& d, int n, u16* a0h, u16* a0l, u16* smem)
{
    float* sE  = (float*)smem;
    float* sAs = sE + 128;
    const int b = blockIdx.x;
    const int tid = threadIdx.x;
    const int lane = tid & 63, wave = tid >> 6;
    float qr[16], wr[16];
    const float* qb = d.qp + (size_t)b*HH;
    #pragma unroll
    for (int j=0;j<8;j++){
        qr[j]   = qb[lane*8 + j];        wr[j]   = d.w2[lane*8 + j];
        qr[8+j] = qb[512 + lane*8 + j];  wr[8+j] = d.w2[512 + lane*8 + j];
    }
    float b2 = d.b2p[0];
    // energy: software-pipelined (load s+1 while computing s)
    {
        const int s0 = wave*32;
        const u16* row0 = d.enc_prj + ((size_t)b*SS + s0)*HH;
        int4 r0 = *(const int4*)(row0 + lane*8);
        int4 r1 = *(const int4*)(row0 + 512 + lane*8);
        for (int ii=0; ii<32; ii++){
            int4 c0 = r0, c1 = r1;
            if (ii < 31){
                const u16* nr = d.enc_prj + ((size_t)b*SS + s0 + ii + 1)*HH;
                r0 = *(const int4*)(nr + lane*8);
                r1 = *(const int4*)(nr + 512 + lane*8);
            }
            const u16* u0 = (const u16*)&c0;
            const u16* u1 = (const u16*)&c1;
            float acc = 0.f;
            #pragma unroll
            for (int j=0;j<8;j++) acc += tanh_(bf2f(u0[j]) + qr[j]) * wr[j];
            #pragma unroll
            for (int j=0;j<8;j++) acc += tanh_(bf2f(u1[j]) + qr[8+j]) * wr[8+j];
            #pragma unroll
            for (int off=32; off; off>>=1) acc += __shfl_xor(acc, off);
            if (lane == 0){
                float e = acc + b2;
                if (d.src[b*SS + s0 + ii] == 0) e = -1e30f;
                sE[s0 + ii] = e;
            }
        }
    }
    __syncthreads();
    if (wave == 0){
        float v0 = sE[lane], v1 = sE[64 + lane];
        float m = fmaxf(v0, v1);
        #pragma unroll
        for (int off=32; off; off>>=1) m = fmaxf(m, __shfl_xor(m, off));
        float p0 = __expf(v0 - m), p1 = __expf(v1 - m);
        float sum = p0 + p1;
        #pragma unroll
        for (int off=32; off; off>>=1) sum += __shfl_xor(sum, off);
        float inv = 1.f / sum;
        float a0 = p0 * inv, a1 = p1 * inv;
        sAs[lane] = a0; sAs[64+lane] = a1;
        float* op = d.out1 + ((size_t)b*(TT-1) + n)*SS;
        op[lane] = a0; op[64+lane] = a1;
    }
    __syncthreads();
    // ctx: unrolled x8 for load ILP (was a 128-iter dependent-load chain)
    int c4 = tid*4;
    float av0=0, av1=0, av2=0, av3=0;
    const u16* eb = d.enc_out + (size_t)b*SS*HH + c4;
    for (int s=0; s<SS; s+=8){
        uint2 u[8];
        #pragma unroll
        for (int k=0;k<8;k++) u[k] = *(const uint2*)(eb + (size_t)(s+k)*HH);
        #pragma unroll
        for (int k=0;k<8;k++){
            float as = sAs[s+k];
            const u16* pu = (const u16*)&u[k];
            av0 += as * bf2f(pu[0]);
            av1 += as * bf2f(pu[1]);
            av2 += as * bf2f(pu[2]);
            av3 += as * bf2f(pu[3]);
        }
    }
    u16* ch = a0h + (size_t)b*2560 + 512 + c4;
    u16* cl = a0l + (size_t)b*2560 + 512 + c4;
    float av[4] = {av0,av1,av2,av3};
    #pragma unroll
    for (int k=0;k<4;k++){
        u16 hi = f2bf(av[k]); ch[k] = hi; cl[k] = f2bf(av[k] - bf2f(hi));
    }
    int tok = d.tgt[b*TT + n];
    const float* ep = d.dec_embed + (size_t)tok*EE;
    u16* ehp = a0h + (size_t)b*2560;
    u16* elp = a0l + (size_t)b*2560;
    #pragma unroll
    for (int k=0;k<2;k++){
        int e = tid*2 + k;
        float x = ep[e];
        u16 hi = f2bf(x);
        ehp[e] = hi; elp[e] = f2bf(x - bf2f(hi));
    }
    __syncthreads();
}

__global__ __launch_bounds__(256)
void dec_mega(DecArgs d)
{
    __shared__ __align__(16) u16 smem[4*64*LDSP];
    const size_t A0SZ = 256*2560, A1SZ = 256*2048;
    unsigned g = 1;

    dec_gemm<1>(d.A1h + 1024, d.A1l + 1024, 2048, d.Wch, d.Wcl, 1024, d.bcq,
                nullptr, nullptr, nullptr, 0, nullptr, nullptr, 0,
                d.qdump, 256, d.qp, 20, smem);
    gridbar(d.bar, g++);

    for (int n = 0; n < 127; n++){
        const int pc = n & 1, pn = 1 - pc;
        attn_phase(d, n, d.A0h + (size_t)pc*A0SZ, d.A0l + (size_t)pc*A0SZ, smem);
        gridbar(d.bar, g++);
        dec_gemm<0>(d.A0h + (size_t)pc*A0SZ, d.A0l + (size_t)pc*A0SZ, 2560,
                    d.W0h, d.W0l, 2560, d.b0p,
                    d.c0,
                    d.A0h + (size_t)pn*A0SZ + 1536, d.A0l + (size_t)pn*A0SZ + 1536, 2560,
                    d.A1h + (size_t)pc*A1SZ,        d.A1l + (size_t)pc*A1SZ,        2048,
                    nullptr, 0, nullptr, 64, smem);
        gridbar(d.bar, g++);
        dec_gemm<0>(d.A1h + (size_t)pc*A1SZ, d.A1l + (size_t)pc*A1SZ, 2048,
                    d.W1h, d.W1l, 2048, d.b1p,
                    d.c1,
                    d.A1h + (size_t)pn*A1SZ + 1024, d.A1l + (size_t)pn*A1SZ + 1024, 2048,
                    nullptr, nullptr, 0,
                    nullptr, 0, nullptr, 64, smem);
        gridbar(d.bar, g++);
        dec_gemm<1>(d.A1h + (size_t)pn*A1SZ + 1024, d.A1l + (size_t)pn*A1SZ + 1024, 2048,
                    d.Wch, d.Wcl, 1024, d.bcq,
                    nullptr, nullptr, nullptr, 0, nullptr, nullptr, 0,
                    d.out0 + (size_t)(n+1)*VV, (long)TT*VV, d.qp, 20, smem);
        gridbar(d.bar, g++);
    }
}

// ---------------- prep / utility kernels ----------------
__global__ void permute_convert_kernel(const float* __restrict__ s, u16* __restrict__ d,
    int hid, int cols, int dld, int doff, int total){
    int i = blockIdx.x*256 + threadIdx.x;
    if (i >= total) return;
    int p = i / cols, c = i - p*cols;
    int j = p >> 2, q = p & 3;
    d[(size_t)p*dld + doff + c] = f2bf(s[((size_t)q*hid + j)*cols + c]);
}
__global__ void permute_convert_split_kernel(const float* __restrict__ s, u16* __restrict__ dh,
    u16* __restrict__ dl, int hid, int cols, int dld, int doff, int total){
    int i = blockIdx.x*256 + threadIdx.x;
    if (i >= total) return;
    int p = i / cols, c = i - p*cols;
    int j = p >> 2, q = p & 3;
    float x = s[((size_t)q*hid + j)*cols + c];
    u16 hi = f2bf(x);
    dh[(size_t)p*dld + doff + c] = hi;
    dl[(size_t)p*dld + doff + c] = f2bf(x - bf2f(hi));
}
__global__ void permute_bias_kernel(const float* __restrict__ s, float* __restrict__ d, int hid){
    int p = blockIdx.x*256 + threadIdx.x;
    if (p >= 4*hid) return;
    int j = p >> 2, q = p & 3;
    d[p] = s[q*hid + j];
}
__global__ void convert_kernel(const float* __restrict__ s, int sld, int soff,
    u16* __restrict__ d, int dld, int cols, int total){
    int i = blockIdx.x*256 + threadIdx.x;
    if (i >= total) return;
    int r = i / cols, c = i - r*cols;
    d[(size_t)r*dld + c] = f2bf(s[(size_t)r*sld + soff + c]);
}
__global__ void convert_split_kernel(const float* __restrict__ s, int sld, int soff,
    u16* __restrict__ dh, u16* __restrict__ dl, int dld, int cols, int total){
    int i = blockIdx.x*256 + threadIdx.x;
    if (i >= total) return;
    int r = i / cols, c = i - r*cols;
    float x = s[(size_t)r*sld + soff + c];
    u16 hi = f2bf(x);
    dh[(size_t)r*dld + c] = hi;
    dl[(size_t)r*dld + c] = f2bf(x - bf2f(hi));
}
__global__ void build_bcq_kernel(const float* __restrict__ fcb, const float* __restrict__ ab1,
    float* __restrict__ d){
    int i = blockIdx.x*256 + threadIdx.x;
    if (i < 256) d[i] = fcb[i];
    else if (i < 1280) d[i] = ab1[i - 256];
}
__global__ void gather_chunk_kernel(const int* __restrict__ src, const float* __restrict__ emb,
    u16* __restrict__ xe, int t0){
    int i = blockIdx.x*256 + threadIdx.x;
    int m = i >> 9, e = i & 511;
    int tl = m >> 8, b = m & 255;
    int tok = src[b*SS + t0 + tl];
    xe[i] = f2bf(emb[(size_t)tok*EE + e]);
}
__global__ void zero_u16_kernel(u16* p, int n){
    int i = blockIdx.x*256 + threadIdx.x; if (i < n) p[i] = 0;
}
__global__ void zero_f32_kernel(float* p, int n){
    int i = blockIdx.x*256 + threadIdx.x; if (i < n) p[i] = 0.f;
}
__global__ void zero_out0_kernel(float* out0){
    int i = blockIdx.x*256 + threadIdx.x;
    int b = i >> 8, v = i & 255;
    out0[(size_t)b*TT*VV + v] = 0.f;
}
__global__ void zero_bar_kernel(unsigned* b){
    int i = threadIdx.x;
    b[i] = 0u; b[i + 256] = 0u;
}
__global__ void dec_init_kernel(const u16* h0f, const u16* h0b, const u16* h1f, const u16* h1b,
    const float* c0f, const float* c0b, const float* c1f, const float* c1b,
    u16* a0h, u16* a0l, u16* a1h, u16* a1l, float* c0, float* c1)
{
    int i = blockIdx.x*256 + threadIdx.x;
    int m = i >> 10, j = i & 1023;
    u16 h0 = (j < 512) ? h0f[m*512 + j] : h0b[m*512 + j - 512];
    u16 h1 = (j < 512) ? h1f[m*512 + j] : h1b[m*512 + j - 512];
    float cc0 = (j < 512) ? c0f[m*512 + j] : c0b[m*512 + j - 512];
    float cc1 = (j < 512) ? c1f[m*512 + j] : c1b[m*512 + j - 512];
    a0h[(size_t)m*2560 + 1536 + j] = h0; a0l[(size_t)m*2560 + 1536 + j] = 0;
    a1h[(size_t)m*2048 + 1024 + j] = h1; a1l[(size_t)m*2048 + 1024 + j] = 0;
    c0[i] = cc0; c1[i] = cc1;
}

// ---------------- host ----------------
extern "C" void kernel_launch(void* const* d_in, const int* in_sizes, int n_in,
                              void* d_out, int out_size, void* d_ws, size_t ws_size,
                              hipStream_t stream)
{
    (void)in_sizes; (void)n_in; (void)out_size;
    const size_t NEED = 230100000;
    if (ws_size < NEED) return;

    const int*   src = (const int*)d_in[0];
    const int*   tgt = (const int*)d_in[1];
    const float* enc_embed = (const float*)d_in[2];
    const float* dec_embed = (const float*)d_in[3];
    const float* ew[4][3] = {
        {(const float*)d_in[4],  (const float*)d_in[5],  (const float*)d_in[6]},
        {(const float*)d_in[7],  (const float*)d_in[8],  (const float*)d_in[9]},
        {(const float*)d_in[10], (const float*)d_in[11], (const float*)d_in[12]},
        {(const float*)d_in[13], (const float*)d_in[14], (const float*)d_in[15]},
    };
    const float* d0_wih = (const float*)d_in[16];
    const float* d0_whh = (const float*)d_in[17];
    const float* d0_b   = (const float*)d_in[18];
    const float* d1_wih = (const float*)d_in[19];
    const float* d1_whh = (const float*)d_in[20];
    const float* d1_b   = (const float*)d_in[21];
    const float* attn_w1 = (const float*)d_in[22];
    const float* attn_b1 = (const float*)d_in[23];
    const float* attn_w2 = (const float*)d_in[24];
    const float* attn_b2 = (const float*)d_in[25];
    const float* fc_w = (const float*)d_in[26];
    const float* fc_b = (const float*)d_in[27];

    float* out0 = (float*)d_out;
    float* out1 = out0 + (size_t)BB*TT*VV;

    char* base = (char*)d_ws;
    size_t off = 0;
    auto alloc = [&](size_t nbytes)->char*{
        char* p = base + off;
        off += (nbytes + 255) & ~(size_t)255;
        return p;
    };
    float* b_e[4];
    for (int d2=0; d2<4; d2++) b_e[d2] = (float*)alloc(2048*4);
    float* b0p = (float*)alloc(4096*4);
    float* b1p = (float*)alloc(4096*4);
    float* bcq = (float*)alloc(1280*4);
    unsigned* bflags = (unsigned*)alloc(2048);
    u16* hbuf    = (u16*)alloc((size_t)8*256*512*2);
    float* cbuf  = (float*)alloc((size_t)4*256*512*4);
    u16* bufA0h = (u16*)alloc((size_t)2*256*2560*2);
    u16* bufA0l = (u16*)alloc((size_t)2*256*2560*2);
    u16* bufA1h = (u16*)alloc((size_t)2*256*2048*2);
    u16* bufA1l = (u16*)alloc((size_t)2*256*2048*2);
    float* c0 = (float*)alloc((size_t)256*1024*4);
    float* c1 = (float*)alloc((size_t)256*1024*4);
    float* qp = (float*)alloc((size_t)256*1024*4);
    float* qdump = (float*)alloc((size_t)256*256*4);
    u16* enc_out = (u16*)alloc((size_t)32768*1024*2);
    u16* x1      = (u16*)alloc((size_t)32768*1024*2);
    u16* enc_prj = x1;
    char* D = alloc(81000000);
    size_t doff = 0;
    auto carve = [&](size_t nbytes)->char*{ char* p = D + doff; doff += nbytes; return p; };
    const int in_dim_e[4] = {512,512,1024,1024};
    u16* wih_e[4]; u16* whh_e[4];
    for (int d2=0; d2<4; d2++){
        wih_e[d2] = (u16*)carve((size_t)2048*in_dim_e[d2]*2);
        whh_e[d2] = (u16*)carve((size_t)2048*512*2);
    }
    u16* w1enc = (u16*)carve((size_t)1024*1024*2);
    u16* xef   = (u16*)carve((size_t)CH*256*512*2);
    u16* xeb   = (u16*)carve((size_t)CH*256*512*2);
    u16* preA  = (u16*)carve((size_t)CH*256*2048*2);
    u16* preB  = (u16*)carve((size_t)CH*256*2048*2);
    doff = 0;
    u16* W0h = (u16*)carve((size_t)4096*2560*2);
    u16* W0l = (u16*)carve((size_t)4096*2560*2);
    u16* W1h = (u16*)carve((size_t)4096*2048*2);
    u16* W1l = (u16*)carve((size_t)4096*2048*2);
    u16* Wch = (u16*)carve((size_t)1280*1024*2);
    u16* Wcl = (u16*)carve((size_t)1280*1024*2);

    const size_t HSZ2 = 256*512;
    const size_t CSZ  = 256*512;

    for (int d2=0; d2<4; d2++){
        int tot = 2048*in_dim_e[d2];
        permute_convert_kernel<<<(tot+255)/256,256,0,stream>>>(ew[d2][0], wih_e[d2], 512, in_dim_e[d2], in_dim_e[d2], 0, tot);
        tot = 2048*512;
        permute_convert_kernel<<<(tot+255)/256,256,0,stream>>>(ew[d2][1], whh_e[d2], 512, 512, 512, 0, tot);
        permute_bias_kernel<<<8,256,0,stream>>>(ew[d2][2], b_e[d2], 512);
    }
    {
        int tw = 1024*1024;
        convert_kernel<<<(tw+255)/256,256,0,stream>>>(attn_w1, 2048, 0, w1enc, 1024, 1024, tw);
    }
    for (int d2=0; d2<4; d2++)
        zero_u16_kernel<<<512,256,0,stream>>>(hbuf + (size_t)(d2*2)*HSZ2, (int)HSZ2);
    zero_f32_kernel<<<2048,256,0,stream>>>(cbuf, 4*(int)CSZ);
    zero_out0_kernel<<<256,256,0,stream>>>(out0);

    for (int layer = 0; layer < 2; layer++){
        const long ldx  = layer ? 1024 : 512;
        const int  dirf = layer*2, dirb = layer*2 + 1;
        for (int c = 0; c < 128/CH; c++){
            const int tf0 = c*CH, tb0 = 128 - CH*(c+1);
            const u16 *Af, *Ab;
            if (layer == 0){
                gather_chunk_kernel<<<CH*512,256,0,stream>>>(src, enc_embed, xef, tf0);
                gather_chunk_kernel<<<CH*512,256,0,stream>>>(src, enc_embed, xeb, tb0);
                Af = xef; Ab = xeb;
            } else {
                Af = x1 + (size_t)tf0*256*1024;
                Ab = x1 + (size_t)tb0*256*1024;
            }
            {
                GArgs a{}, b{};
                a.A = Af; a.lda = ldx; a.Bw = wih_e[dirf]; a.K = ldx; a.bias = b_e[dirf];
                a.Cb = preA; a.ldc = 2048;
                b.A = Ab; b.lda = ldx; b.Bw = wih_e[dirb]; b.K = ldx; b.bias = b_e[dirb];
                b.Cb = preB; b.ldc = 2048;
                gemm2_kernel<2,2><<<dim3(16, CH*2, 2),256,0,stream>>>(a, b);
            }
            for (int i = 0; i < CH; i++){
                int t = c*CH + i;
                GArgs f{}, bq{};
                f.A = hbuf + (size_t)(dirf*2 + (t&1))*HSZ2; f.lda = 512;
                f.Bw = whh_e[dirf]; f.K = 512;
                f.pre = preA + (size_t)i*256*2048; f.ldpre = 2048;
                f.cst = cbuf + (size_t)dirf*CSZ; f.hid = 512;
                if (layer == 0){ f.h1 = x1 + (size_t)t*256*1024;      f.ldh1 = 1024; }
                else           { f.h1 = enc_out + (size_t)t*1024;     f.ldh1 = (long)SS*1024; }
                f.h2 = hbuf + (size_t)(dirf*2 + ((t+1)&1))*HSZ2; f.ldh2 = 512;
                bq = f;
                bq.A = hbuf + (size_t)(dirb*2 + (t&1))*HSZ2;
                bq.Bw = whh_e[dirb];
                bq.pre = preB + (size_t)(CH-1-i)*256*2048;
                bq.cst = cbuf + (size_t)dirb*CSZ;
                if (layer == 0){ bq.h1 = x1 + (size_t)(127-t)*256*1024 + 512; }
                else           { bq.h1 = enc_out + (size_t)(127-t)*1024 + 512; }
                bq.h2 = hbuf + (size_t)(dirb*2 + ((t+1)&1))*HSZ2;
                lstm_step2_kernel<1,2><<<dim3(16,4,2),128,0,stream>>>(f,bq);
            }
        }
    }
    {
        GArgs a{}; a.A = enc_out; a.lda = 1024; a.Bw = w1enc; a.K = 1024;
        a.Cb = enc_prj; a.ldc = 1024;
        gemm_kernel<2,2,0,0><<<dim3(8,256),256,0,stream>>>(a);
    }
    {
        int tot = 4096*1536;
        permute_convert_split_kernel<<<(tot+255)/256,256,0,stream>>>(d0_wih, W0h, W0l, 1024, 1536, 2560, 0, tot);
        tot = 4096*1024;
        permute_convert_split_kernel<<<(tot+255)/256,256,0,stream>>>(d0_whh, W0h, W0l, 1024, 1024, 2560, 1536, tot);
        permute_bias_kernel<<<16,256,0,stream>>>(d0_b, b0p, 1024);
        tot = 4096*1024;
        permute_convert_split_kernel<<<(tot+255)/256,256,0,stream>>>(d1_wih, W1h, W1l, 1024, 1024, 2048, 0, tot);
        permute_convert_split_kernel<<<(tot+255)/256,256,0,stream>>>(d1_whh, W1h, W1l, 1024, 1024, 2048, 1024, tot);
        permute_bias_kernel<<<16,256,0,stream>>>(d1_b, b1p, 1024);
        int tf = 256*1024;
        convert_split_kernel<<<(tf+255)/256,256,0,stream>>>(fc_w, 1024, 0, Wch, Wcl, 1024, 1024, tf);
        int tq = 1024*1024;
        convert_split_kernel<<<(tq+255)/256,256,0,stream>>>(attn_w1, 2048, 1024,
            Wch + (size_t)256*1024, Wcl + (size_t)256*1024, 1024, 1024, tq);
        build_bcq_kernel<<<5,256,0,stream>>>(fc_b, attn_b1, bcq);
    }
    dec_init_kernel<<<1024,256,0,stream>>>(
        hbuf + 0*2*HSZ2, hbuf + 1*2*HSZ2, hbuf + 2*2*HSZ2, hbuf + 3*2*HSZ2,
        cbuf + 0*CSZ, cbuf + 1*CSZ, cbuf + 2*CSZ, cbuf + 3*CSZ,
        bufA0h, bufA0l, bufA1h, bufA1l, c0, c1);
    zero_bar_kernel<<<1,256,0,stream>>>(bflags);

    DecArgs da{};
    da.enc_prj = enc_prj; da.enc_out = enc_out;
    da.w2 = attn_w2; da.b2p = attn_b2;
    da.src = src; da.tgt = tgt; da.dec_embed = dec_embed;
    da.out0 = out0; da.out1 = out1;
    da.A0h = bufA0h; da.A0l = bufA0l; da.A1h = bufA1h; da.A1l = bufA1l;
    da.c0 = c0; da.c1 = c1; da.qp = qp; da.qdump = qdump;
    da.W0h = W0h; da.W0l = W0l; da.W1h = W1h; da.W1l = W1l;
    da.Wch = Wch; da.Wcl = Wcl;
    da.b0p = b0p; da.b1p = b1p; da.bcq = bcq;
    da.bar = bflags;
    dec_mega<<<256,256,0,stream>>>(da);
}

// Round 7
// 28298.709 us; speedup vs baseline: 3.3608x; 2.5430x over previous
//
#include <hip/hip_runtime.h>
#include <stdint.h>

typedef unsigned short u16;
typedef __attribute__((ext_vector_type(8))) short short8;
typedef __attribute__((ext_vector_type(4))) float f32x4;

#define BB 256
#define SS 128
#define TT 128
#define EE 512
#define HH 1024
#define VV 256

#define BK 64
#define LDSP 72   // padded LDS row length in bf16 elems (144 B = 9*16, keeps 16B alignment)
#define CH 8      // encoder pre-GEMM chunk (timesteps)

__device__ __forceinline__ float bf2f(u16 u){
    union { unsigned int i; float f; } v; v.i = ((unsigned int)u) << 16; return v.f;
}
__device__ __forceinline__ u16 f2bf(float f){
    union { float f; unsigned int i; } v; v.f = f;
    return (u16)((v.i + 0x7fffu + ((v.i >> 16) & 1u)) >> 16);
}
__device__ __forceinline__ float rcp_(float x){ return __builtin_amdgcn_rcpf(x); }
__device__ __forceinline__ float sigm_(float x){ return rcp_(1.f + __expf(-x)); }
__device__ __forceinline__ float tanh_(float x){ return 1.f - 2.f*rcp_(__expf(2.f*x) + 1.f); }

struct GArgs {
    const u16* A;  const u16* A2; long lda;
    const u16* Bw; const u16* B2; long K;
    const float* bias;
    u16* Cb; float* Cf; long ldc;
    const u16* pre; long ldpre;
    float* cst; long hid;
    u16* h1; u16* h1l; long ldh1;
    u16* h2; u16* h2l; long ldh2;
};

// ===== R3-proven GEMM core (no register prefetch) — encoder path =====
template<int BMW, int BNW, int MODE, int SPLIT>
__device__ __forceinline__ void gemm_core(const GArgs& g)
{
    constexpr int BM = BMW*64, BN = BNW*64;
    constexpr int NT = BMW*BNW*64;
    constexpr int AE = BM*LDSP, BE = BN*LDSP;
    static_assert((BM*8) % NT == 0 && (BN*8) % NT == 0, "staging");
    __shared__ __align__(16) u16 sA[(SPLIT+1)*AE];
    __shared__ __align__(16) u16 sB[(SPLIT+1)*BE];
    const int tid = threadIdx.x;
    const int lane = tid & 63, wave = tid >> 6;
    const int wn = wave % BNW, wm = wave / BNW;
    const int l15 = lane & 15, quad = lane >> 4;
    const long m0 = (long)blockIdx.y * BM, n0 = (long)blockIdx.x * BN;

    f32x4 acc[4][4];
    #pragma unroll
    for (int a=0;a<4;a++)
    #pragma unroll
    for (int c=0;c<4;c++){ f32x4 z = {0.f,0.f,0.f,0.f}; acc[a][c] = z; }

    for (long k0 = 0; k0 < g.K; k0 += BK){
        #pragma unroll
        for (int i = 0; i < BM*8/NT; i++){
            int c = tid + i*NT;
            int r = c >> 3, c8 = (c & 7) * 8;
            *(int4*)&sA[r*LDSP + c8] = *(const int4*)(g.A + (m0 + r)*g.lda + k0 + c8);
            if (SPLIT)
                *(int4*)&sA[AE + r*LDSP + c8] = *(const int4*)(g.A2 + (m0 + r)*g.lda + k0 + c8);
        }
        #pragma unroll
        for (int i = 0; i < BN*8/NT; i++){
            int c = tid + i*NT;
            int r = c >> 3, c8 = (c & 7) * 8;
            *(int4*)&sB[r*LDSP + c8] = *(const int4*)(g.Bw + (n0 + r)*g.K + k0 + c8);
            if (SPLIT)
                *(int4*)&sB[BE + r*LDSP + c8] = *(const int4*)(g.B2 + (n0 + r)*g.K + k0 + c8);
        }
        __syncthreads();
        #pragma unroll
        for (int ks = 0; ks < 2; ks++){
            const int ko = ks*32 + quad*8;
            short8 ah[4], bh[4], al[4], bl[4];
            #pragma unroll
            for (int mi=0; mi<4; mi++){
                int ra = (wm*64 + mi*16 + l15)*LDSP + ko;
                ah[mi] = *(const short8*)&sA[ra];
                if (SPLIT) al[mi] = *(const short8*)&sA[AE + ra];
            }
            #pragma unroll
            for (int ni=0; ni<4; ni++){
                int rb = (wn*64 + ni*16 + l15)*LDSP + ko;
                bh[ni] = *(const short8*)&sB[rb];
                if (SPLIT) bl[ni] = *(const short8*)&sB[BE + rb];
            }
            #pragma unroll
            for (int mi=0; mi<4; mi++)
            #pragma unroll
            for (int ni=0; ni<4; ni++){
                acc[mi][ni] = __builtin_amdgcn_mfma_f32_16x16x32_bf16(ah[mi], bh[ni], acc[mi][ni], 0,0,0);
                if (SPLIT){
                    acc[mi][ni] = __builtin_amdgcn_mfma_f32_16x16x32_bf16(al[mi], bh[ni], acc[mi][ni], 0,0,0);
                    acc[mi][ni] = __builtin_amdgcn_mfma_f32_16x16x32_bf16(ah[mi], bl[ni], acc[mi][ni], 0,0,0);
                }
            }
        }
        __syncthreads();
    }

    #pragma unroll
    for (int mi=0; mi<4; mi++)
    #pragma unroll
    for (int ni=0; ni<4; ni++)
    #pragma unroll
    for (int r=0; r<4; r++){
        long row = m0 + wm*64 + mi*16 + quad*4 + r;
        long col = n0 + wn*64 + ni*16 + l15;
        float v = acc[mi][ni][r];
        if (g.bias) v += g.bias[col];
        if (MODE == 2){
            if (g.pre) v += bf2f(g.pre[row*g.ldpre + col]);
            float gf = __shfl_xor(v, 1);
            float gg = __shfl_xor(v, 2);
            float go = __shfl_xor(v, 3);
            if ((lane & 3) == 0){
                long j = col >> 2;
                float co = g.cst[row*g.hid + j];
                float cn = sigm_(gf)*co + sigm_(v)*tanh_(gg);
                g.cst[row*g.hid + j] = cn;
                float hn = sigm_(go)*tanh_(cn);
                u16 hb = f2bf(hn);
                u16 lb = 0;
                if (SPLIT) lb = f2bf(hn - bf2f(hb));
                g.h1[row*g.ldh1 + j] = hb;
                if (SPLIT) g.h1l[row*g.ldh1 + j] = lb;
                if (g.h2){
                    g.h2[row*g.ldh2 + j] = hb;
                    if (SPLIT) g.h2l[row*g.ldh2 + j] = lb;
                }
            }
        } else if (MODE == 1){
            g.Cf[row*g.ldc + col] = v;
        } else {
            g.Cb[row*g.ldc + col] = f2bf(v);
        }
    }
}

template<int BMW,int BNW,int MODE,int SPLIT>
__global__ __launch_bounds__(BMW*BNW*64)
void gemm_kernel(GArgs g){ gemm_core<BMW,BNW,MODE,SPLIT>(g); }

template<int BMW,int BNW>
__global__ __launch_bounds__(BMW*BNW*64)
void lstm_step2_kernel(GArgs gf, GArgs gb){
    if (blockIdx.z == 0) gemm_core<BMW,BNW,2,0>(gf);
    else                 gemm_core<BMW,BNW,2,0>(gb);
}
template<int BMW,int BNW>
__global__ __launch_bounds__(BMW*BNW*64)
void gemm2_kernel(GArgs ga, GArgs gb){
    if (blockIdx.z == 0) gemm_core<BMW,BNW,0,0>(ga);
    else                 gemm_core<BMW,BNW,0,0>(gb);
}

// ==================== decoder phase kernels (R6 mega phases, standalone) ====================
struct DG {
    const u16 *Ah, *Al; long lda;
    const u16 *Bh, *Bl; long K;
    const float* bias;
    float* cst;                      // EPI0: c state
    u16 *h1, *h1l; long ldh1;
    u16 *h2, *h2l; long ldh2;
    float* Cf; long ldc;             // EPI1: logits dest
    float* qp;                       // EPI1: q_proj dest
    int nblk;
};

// split-bf16 GEMM, 64x64 block tile, 4 waves as 2x2 of 32x32.
// EPI: 0 = LSTM cell epilogue, 1 = dual f32 (col<256 -> Cf, else -> qp)
template<int EPI>
__global__ __launch_bounds__(256)
void dgemm_kernel(DG d)
{
    __shared__ __align__(16) u16 smem[4*64*LDSP];
    const int bid = blockIdx.x;
    const int by = bid / d.nblk, bx = bid - by*d.nblk;
    const long m0 = (long)by*64, n0 = (long)bx*64;
    u16* sAh = smem;
    u16* sAl = smem + 64*LDSP;
    u16* sBh = smem + 2*64*LDSP;
    u16* sBl = smem + 3*64*LDSP;
    const int tid = threadIdx.x;
    const int lane = tid & 63, wave = tid >> 6;
    const int wm2 = wave >> 1, wn2 = wave & 1;
    const int l15 = lane & 15, quad = lane >> 4;

    f32x4 acc[2][2];
    #pragma unroll
    for (int a=0;a<2;a++)
    #pragma unroll
    for (int c=0;c<2;c++){ f32x4 z = {0.f,0.f,0.f,0.f}; acc[a][c] = z; }

    for (long k0 = 0; k0 < d.K; k0 += BK){
        #pragma unroll
        for (int i = 0; i < 2; i++){
            int idx = tid + i*256;
            int r = idx >> 3, c8 = (idx & 7) * 8;
            *(int4*)&sAh[r*LDSP + c8] = *(const int4*)(d.Ah + (m0 + r)*d.lda + k0 + c8);
            *(int4*)&sAl[r*LDSP + c8] = *(const int4*)(d.Al + (m0 + r)*d.lda + k0 + c8);
            *(int4*)&sBh[r*LDSP + c8] = *(const int4*)(d.Bh + (n0 + r)*d.K + k0 + c8);
            *(int4*)&sBl[r*LDSP + c8] = *(const int4*)(d.Bl + (n0 + r)*d.K + k0 + c8);
        }
        __syncthreads();
        #pragma unroll
        for (int ks = 0; ks < 2; ks++){
            const int ko = ks*32 + quad*8;
            short8 ah[2], al[2], bh[2], bl[2];
            #pragma unroll
            for (int mi=0; mi<2; mi++){
                int ra = (wm2*32 + mi*16 + l15)*LDSP + ko;
                ah[mi] = *(const short8*)&sAh[ra];
                al[mi] = *(const short8*)&sAl[ra];
            }
            #pragma unroll
            for (int ni=0; ni<2; ni++){
                int rb = (wn2*32 + ni*16 + l15)*LDSP + ko;
                bh[ni] = *(const short8*)&sBh[rb];
                bl[ni] = *(const short8*)&sBl[rb];
            }
            #pragma unroll
            for (int mi=0; mi<2; mi++)
            #pragma unroll
            for (int ni=0; ni<2; ni++){
                acc[mi][ni] = __builtin_amdgcn_mfma_f32_16x16x32_bf16(ah[mi], bh[ni], acc[mi][ni], 0,0,0);
                acc[mi][ni] = __builtin_amdgcn_mfma_f32_16x16x32_bf16(al[mi], bh[ni], acc[mi][ni], 0,0,0);
                acc[mi][ni] = __builtin_amdgcn_mfma_f32_16x16x32_bf16(ah[mi], bl[ni], acc[mi][ni], 0,0,0);
            }
        }
        __syncthreads();
    }

    #pragma unroll
    for (int mi=0; mi<2; mi++)
    #pragma unroll
    for (int ni=0; ni<2; ni++)
    #pragma unroll
    for (int r=0; r<4; r++){
        long row = m0 + wm2*32 + mi*16 + quad*4 + r;
        long col = n0 + wn2*32 + ni*16 + l15;
        float v = acc[mi][ni][r] + d.bias[col];
        if (EPI == 0){
            float gf = __shfl_xor(v, 1);
            float gg = __shfl_xor(v, 2);
            float go = __shfl_xor(v, 3);
            if ((lane & 3) == 0){
                long j = col >> 2;
                float co = d.cst[row*1024 + j];
                float cn = sigm_(gf)*co + sigm_(v)*tanh_(gg);
                d.cst[row*1024 + j] = cn;
                float hn = sigm_(go)*tanh_(cn);
                u16 hb = f2bf(hn);
                u16 lb = f2bf(hn - bf2f(hb));
                d.h1[row*d.ldh1 + j] = hb;  d.h1l[row*d.ldh1 + j] = lb;
                if (d.h2){ d.h2[row*d.ldh2 + j] = hb;  d.h2l[row*d.ldh2 + j] = lb; }
            }
        } else {
            if (col < 256) d.Cf[row*d.ldc + col] = v;
            else           d.qp[row*1024 + (col - 256)] = v;
        }
    }
}

// attention step (R6-improved: pipelined energy, unrolled ctx)
__global__ __launch_bounds__(256)
void attn2_kernel(const u16* __restrict__ enc_prj, const u16* __restrict__ enc_out,
                  const float* __restrict__ qp, const float* __restrict__ w2,
                  const float* __restrict__ b2p,
                  const int* __restrict__ src, const int* __restrict__ tgt,
                  const float* __restrict__ dec_embed,
                  float* __restrict__ out1,
                  u16* __restrict__ a0h, u16* __restrict__ a0l, int n)
{
    __shared__ float sE[SS];
    __shared__ float sAs[SS];
    const int b = blockIdx.x;
    const int tid = threadIdx.x;
    const int lane = tid & 63, wave = tid >> 6;
    float qr[16], wr[16];
    const float* qb = qp + (size_t)b*HH;
    #pragma unroll
    for (int j=0;j<8;j++){
        qr[j]   = qb[lane*8 + j];        wr[j]   = w2[lane*8 + j];
        qr[8+j] = qb[512 + lane*8 + j];  wr[8+j] = w2[512 + lane*8 + j];
    }
    float b2 = b2p[0];
    {
        const int s0 = wave*32;
        const u16* row0 = enc_prj + ((size_t)b*SS + s0)*HH;
        int4 r0 = *(const int4*)(row0 + lane*8);
        int4 r1 = *(const int4*)(row0 + 512 + lane*8);
        for (int ii=0; ii<32; ii++){
            int4 c0 = r0, c1 = r1;
            if (ii < 31){
                const u16* nr = enc_prj + ((size_t)b*SS + s0 + ii + 1)*HH;
                r0 = *(const int4*)(nr + lane*8);
                r1 = *(const int4*)(nr + 512 + lane*8);
            }
            const u16* u0 = (const u16*)&c0;
            const u16* u1 = (const u16*)&c1;
            float acc = 0.f;
            #pragma unroll
            for (int j=0;j<8;j++) acc += tanh_(bf2f(u0[j]) + qr[j]) * wr[j];
            #pragma unroll
            for (int j=0;j<8;j++) acc += tanh_(bf2f(u1[j]) + qr[8+j]) * wr[8+j];
            #pragma unroll
            for (int off=32; off; off>>=1) acc += __shfl_xor(acc, off);
            if (lane == 0){
                float e = acc + b2;
                if (src[b*SS + s0 + ii] == 0) e = -1e30f;
                sE[s0 + ii] = e;
            }
        }
    }
    __syncthreads();
    if (wave == 0){
        float v0 = sE[lane], v1 = sE[64 + lane];
        float m = fmaxf(v0, v1);
        #pragma unroll
        for (int off=32; off; off>>=1) m = fmaxf(m, __shfl_xor(m, off));
        float p0 = __expf(v0 - m), p1 = __expf(v1 - m);
        float sum = p0 + p1;
        #pragma unroll
        for (int off=32; off; off>>=1) sum += __shfl_xor(sum, off);
        float inv = 1.f / sum;
        float a0 = p0 * inv, a1 = p1 * inv;
        sAs[lane] = a0; sAs[64+lane] = a1;
        float* op = out1 + ((size_t)b*(TT-1) + n)*SS;
        op[lane] = a0; op[64+lane] = a1;
    }
    __syncthreads();
    int c4 = tid*4;
    float av0=0, av1=0, av2=0, av3=0;
    const u16* eb = enc_out + (size_t)b*SS*HH + c4;
    for (int s=0; s<SS; s+=8){
        uint2 u[8];
        #pragma unroll
        for (int k=0;k<8;k++) u[k] = *(const uint2*)(eb + (size_t)(s+k)*HH);
        #pragma unroll
        for (int k=0;k<8;k++){
            float as = sAs[s+k];
            const u16* pu = (const u16*)&u[k];
            av0 += as * bf2f(pu[0]);
            av1 += as * bf2f(pu[1]);
            av2 += as * bf2f(pu[2]);
            av3 += as * bf2f(pu[3]);
        }
    }
    u16* ch = a0h + (size_t)b*2560 + 512 + c4;
    u16* cl = a0l + (size_t)b*2560 + 512 + c4;
    float av[4] = {av0,av1,av2,av3};
    #pragma unroll
    for (int k=0;k<4;k++){
        u16 hi = f2bf(av[k]); ch[k] = hi; cl[k] = f2bf(av[k] - bf2f(hi));
    }
    int tok = tgt[b*TT + n];
    const float* ep = dec_embed + (size_t)tok*EE;
    u16* ehp = a0h + (size_t)b*2560;
    u16* elp = a0l + (size_t)b*2560;
    #pragma unroll
    for (int k=0;k<2;k++){
        int e = tid*2 + k;
        float x = ep[e];
        u16 hi = f2bf(x);
        ehp[e] = hi; elp[e] = f2bf(x - bf2f(hi));
    }
}

// ---------------- prep / utility kernels ----------------
__global__ void permute_convert_kernel(const float* __restrict__ s, u16* __restrict__ d,
    int hid, int cols, int dld, int doff, int total){
    int i = blockIdx.x*256 + threadIdx.x;
    if (i >= total) return;
    int p = i / cols, c = i - p*cols;
    int j = p >> 2, q = p & 3;
    d[(size_t)p*dld + doff + c] = f2bf(s[((size_t)q*hid + j)*cols + c]);
}
__global__ void permute_convert_split_kernel(const float* __restrict__ s, u16* __restrict__ dh,
    u16* __restrict__ dl, int hid, int cols, int dld, int doff, int total){
    int i = blockIdx.x*256 + threadIdx.x;
    if (i >= total) return;
    int p = i / cols, c = i - p*cols;
    int j = p >> 2, q = p & 3;
    float x = s[((size_t)q*hid + j)*cols + c];
    u16 hi = f2bf(x);
    dh[(size_t)p*dld + doff + c] = hi;
    dl[(size_t)p*dld + doff + c] = f2bf(x - bf2f(hi));
}
__global__ void permute_bias_kernel(const float* __restrict__ s, float* __restrict__ d, int hid){
    int p = blockIdx.x*256 + threadIdx.x;
    if (p >= 4*hid) return;
    int j = p >> 2, q = p & 3;
    d[p] = s[q*hid + j];
}
__global__ void convert_kernel(const float* __restrict__ s, int sld, int soff,
    u16* __restrict__ d, int dld, int cols, int total){
    int i = blockIdx.x*256 + threadIdx.x;
    if (i >= total) return;
    int r = i / cols, c = i - r*cols;
    d[(size_t)r*dld + c] = f2bf(s[(size_t)r*sld + soff + c]);
}
__global__ void convert_split_kernel(const float* __restrict__ s, int sld, int soff,
    u16* __restrict__ dh, u16* __restrict__ dl, int dld, int cols, int total){
    int i = blockIdx.x*256 + threadIdx.x;
    if (i >= total) return;
    int r = i / cols, c = i - r*cols;
    float x = s[(size_t)r*sld + soff + c];
    u16 hi = f2bf(x);
    dh[(size_t)r*dld + c] = hi;
    dl[(size_t)r*dld + c] = f2bf(x - bf2f(hi));
}
__global__ void build_bcq_kernel(const float* __restrict__ fcb, const float* __restrict__ ab1,
    float* __restrict__ d){
    int i = blockIdx.x*256 + threadIdx.x;
    if (i < 256) d[i] = fcb[i];
    else if (i < 1280) d[i] = ab1[i - 256];
}
__global__ void gather_chunk_kernel(const int* __restrict__ src, const float* __restrict__ emb,
    u16* __restrict__ xe, int t0){
    int i = blockIdx.x*256 + threadIdx.x;
    int m = i >> 9, e = i & 511;
    int tl = m >> 8, b = m & 255;
    int tok = src[b*SS + t0 + tl];
    xe[i] = f2bf(emb[(size_t)tok*EE + e]);
}
__global__ void zero_u16_kernel(u16* p, int n){
    int i = blockIdx.x*256 + threadIdx.x; if (i < n) p[i] = 0;
}
__global__ void zero_f32_kernel(float* p, int n){
    int i = blockIdx.x*256 + threadIdx.x; if (i < n) p[i] = 0.f;
}
__global__ void zero_out0_kernel(float* out0){
    int i = blockIdx.x*256 + threadIdx.x;
    int b = i >> 8, v = i & 255;
    out0[(size_t)b*TT*VV + v] = 0.f;
}
__global__ void dec_init_kernel(const u16* h0f, const u16* h0b, const u16* h1f, const u16* h1b,
    const float* c0f, const float* c0b, const float* c1f, const float* c1b,
    u16* a0h, u16* a0l, u16* a1h, u16* a1l, float* c0, float* c1)
{
    int i = blockIdx.x*256 + threadIdx.x;
    int m = i >> 10, j = i & 1023;
    u16 h0 = (j < 512) ? h0f[m*512 + j] : h0b[m*512 + j - 512];
    u16 h1 = (j < 512) ? h1f[m*512 + j] : h1b[m*512 + j - 512];
    float cc0 = (j < 512) ? c0f[m*512 + j] : c0b[m*512 + j - 512];
    float cc1 = (j < 512) ? c1f[m*512 + j] : c1b[m*512 + j - 512];
    a0h[(size_t)m*2560 + 1536 + j] = h0; a0l[(size_t)m*2560 + 1536 + j] = 0;
    a1h[(size_t)m*2048 + 1024 + j] = h1; a1l[(size_t)m*2048 + 1024 + j] = 0;
    c0[i] = cc0; c1[i] = cc1;
}

// ---------------- host ----------------
extern "C" void kernel_launch(void* const* d_in, const int* in_sizes, int n_in,
                              void* d_out, int out_size, void* d_ws, size_t ws_size,
                              hipStream_t stream)
{
    (void)in_sizes; (void)n_in; (void)out_size;
    const size_t NEED = 230100000;
    if (ws_size < NEED) return;

    const int*   src = (const int*)d_in[0];
    const int*   tgt = (const int*)d_in[1];
    const float* enc_embed = (const float*)d_in[2];
    const float* dec_embed = (const float*)d_in[3];
    const float* ew[4][3] = {
        {(const float*)d_in[4],  (const float*)d_in[5],  (const float*)d_in[6]},
        {(const float*)d_in[7],  (const float*)d_in[8],  (const float*)d_in[9]},
        {(const float*)d_in[10], (const float*)d_in[11], (const float*)d_in[12]},
        {(const float*)d_in[13], (const float*)d_in[14], (const float*)d_in[15]},
    };
    const float* d0_wih = (const float*)d_in[16];
    const float* d0_whh = (const float*)d_in[17];
    const float* d0_b   = (const float*)d_in[18];
    const float* d1_wih = (const float*)d_in[19];
    const float* d1_whh = (const float*)d_in[20];
    const float* d1_b   = (const float*)d_in[21];
    const float* attn_w1 = (const float*)d_in[22];
    const float* attn_b1 = (const float*)d_in[23];
    const float* attn_w2 = (const float*)d_in[24];
    const float* attn_b2 = (const float*)d_in[25];
    const float* fc_w = (const float*)d_in[26];
    const float* fc_b = (const float*)d_in[27];

    float* out0 = (float*)d_out;
    float* out1 = out0 + (size_t)BB*TT*VV;

    char* base = (char*)d_ws;
    size_t off = 0;
    auto alloc = [&](size_t nbytes)->char*{
        char* p = base + off;
        off += (nbytes + 255) & ~(size_t)255;
        return p;
    };
    float* b_e[4];
    for (int d2=0; d2<4; d2++) b_e[d2] = (float*)alloc(2048*4);
    float* b0p = (float*)alloc(4096*4);
    float* b1p = (float*)alloc(4096*4);
    float* bcq = (float*)alloc(1280*4);
    u16* hbuf    = (u16*)alloc((size_t)8*256*512*2);
    float* cbuf  = (float*)alloc((size_t)4*256*512*4);
    u16* bufA0h = (u16*)alloc((size_t)2*256*2560*2);
    u16* bufA0l = (u16*)alloc((size_t)2*256*2560*2);
    u16* bufA1h = (u16*)alloc((size_t)2*256*2048*2);
    u16* bufA1l = (u16*)alloc((size_t)2*256*2048*2);
    float* c0 = (float*)alloc((size_t)256*1024*4);
    float* c1 = (float*)alloc((size_t)256*1024*4);
    float* qp = (float*)alloc((size_t)256*1024*4);
    float* qdump = (float*)alloc((size_t)256*256*4);
    u16* enc_out = (u16*)alloc((size_t)32768*1024*2);
    u16* x1      = (u16*)alloc((size_t)32768*1024*2);
    u16* enc_prj = x1;
    char* D = alloc(81000000);
    size_t doff = 0;
    auto carve = [&](size_t nbytes)->char*{ char* p = D + doff; doff += nbytes; return p; };
    const int in_dim_e[4] = {512,512,1024,1024};
    u16* wih_e[4]; u16* whh_e[4];
    for (int d2=0; d2<4; d2++){
        wih_e[d2] = (u16*)carve((size_t)2048*in_dim_e[d2]*2);
        whh_e[d2] = (u16*)carve((size_t)2048*512*2);
    }
    u16* w1enc = (u16*)carve((size_t)1024*1024*2);
    u16* xef   = (u16*)carve((size_t)CH*256*512*2);
    u16* xeb   = (u16*)carve((size_t)CH*256*512*2);
    u16* preA  = (u16*)carve((size_t)CH*256*2048*2);
    u16* preB  = (u16*)carve((size_t)CH*256*2048*2);
    doff = 0;
    u16* W0h = (u16*)carve((size_t)4096*2560*2);
    u16* W0l = (u16*)carve((size_t)4096*2560*2);
    u16* W1h = (u16*)carve((size_t)4096*2048*2);
    u16* W1l = (u16*)carve((size_t)4096*2048*2);
    u16* Wch = (u16*)carve((size_t)1280*1024*2);
    u16* Wcl = (u16*)carve((size_t)1280*1024*2);

    const size_t HSZ2 = 256*512;
    const size_t CSZ  = 256*512;
    const size_t A0SZ = 256*2560, A1SZ = 256*2048;

    // ---- encoder weight prep ----
    for (int d2=0; d2<4; d2++){
        int tot = 2048*in_dim_e[d2];
        permute_convert_kernel<<<(tot+255)/256,256,0,stream>>>(ew[d2][0], wih_e[d2], 512, in_dim_e[d2], in_dim_e[d2], 0, tot);
        tot = 2048*512;
        permute_convert_kernel<<<(tot+255)/256,256,0,stream>>>(ew[d2][1], whh_e[d2], 512, 512, 512, 0, tot);
        permute_bias_kernel<<<8,256,0,stream>>>(ew[d2][2], b_e[d2], 512);
    }
    {
        int tw = 1024*1024;
        convert_kernel<<<(tw+255)/256,256,0,stream>>>(attn_w1, 2048, 0, w1enc, 1024, 1024, tw);
    }
    for (int d2=0; d2<4; d2++)
        zero_u16_kernel<<<512,256,0,stream>>>(hbuf + (size_t)(d2*2)*HSZ2, (int)HSZ2);
    zero_f32_kernel<<<2048,256,0,stream>>>(cbuf, 4*(int)CSZ);
    zero_out0_kernel<<<256,256,0,stream>>>(out0);

    // ---- encoder: chunked pre-GEMMs interleaved with scan ----
    for (int layer = 0; layer < 2; layer++){
        const long ldx  = layer ? 1024 : 512;
        const int  dirf = layer*2, dirb = layer*2 + 1;
        for (int c = 0; c < 128/CH; c++){
            const int tf0 = c*CH, tb0 = 128 - CH*(c+1);
            const u16 *Af, *Ab;
            if (layer == 0){
                gather_chunk_kernel<<<CH*512,256,0,stream>>>(src, enc_embed, xef, tf0);
                gather_chunk_kernel<<<CH*512,256,0,stream>>>(src, enc_embed, xeb, tb0);
                Af = xef; Ab = xeb;
            } else {
                Af = x1 + (size_t)tf0*256*1024;
                Ab = x1 + (size_t)tb0*256*1024;
            }
            {
                GArgs a{}, b{};
                a.A = Af; a.lda = ldx; a.Bw = wih_e[dirf]; a.K = ldx; a.bias = b_e[dirf];
                a.Cb = preA; a.ldc = 2048;
                b.A = Ab; b.lda = ldx; b.Bw = wih_e[dirb]; b.K = ldx; b.bias = b_e[dirb];
                b.Cb = preB; b.ldc = 2048;
                gemm2_kernel<2,2><<<dim3(16, CH*2, 2),256,0,stream>>>(a, b);
            }
            for (int i = 0; i < CH; i++){
                int t = c*CH + i;
                GArgs f{}, bq{};
                f.A = hbuf + (size_t)(dirf*2 + (t&1))*HSZ2; f.lda = 512;
                f.Bw = whh_e[dirf]; f.K = 512;
                f.pre = preA + (size_t)i*256*2048; f.ldpre = 2048;
                f.cst = cbuf + (size_t)dirf*CSZ; f.hid = 512;
                if (layer == 0){ f.h1 = x1 + (size_t)t*256*1024;      f.ldh1 = 1024; }
                else           { f.h1 = enc_out + (size_t)t*1024;     f.ldh1 = (long)SS*1024; }
                f.h2 = hbuf + (size_t)(dirf*2 + ((t+1)&1))*HSZ2; f.ldh2 = 512;
                bq = f;
                bq.A = hbuf + (size_t)(dirb*2 + (t&1))*HSZ2;
                bq.Bw = whh_e[dirb];
                bq.pre = preB + (size_t)(CH-1-i)*256*2048;
                bq.cst = cbuf + (size_t)dirb*CSZ;
                if (layer == 0){ bq.h1 = x1 + (size_t)(127-t)*256*1024 + 512; }
                else           { bq.h1 = enc_out + (size_t)(127-t)*1024 + 512; }
                bq.h2 = hbuf + (size_t)(dirb*2 + ((t+1)&1))*HSZ2;
                lstm_step2_kernel<1,2><<<dim3(16,4,2),128,0,stream>>>(f,bq);
            }
        }
    }
    // ---- enc_proj = enc_out @ w1_enc^T ----
    {
        GArgs a{}; a.A = enc_out; a.lda = 1024; a.Bw = w1enc; a.K = 1024;
        a.Cb = enc_prj; a.ldc = 1024;
        gemm_kernel<2,2,0,0><<<dim3(8,256),256,0,stream>>>(a);
    }
    // ---- decoder weight prep ----
    {
        int tot = 4096*1536;
        permute_convert_split_kernel<<<(tot+255)/256,256,0,stream>>>(d0_wih, W0h, W0l, 1024, 1536, 2560, 0, tot);
        tot = 4096*1024;
        permute_convert_split_kernel<<<(tot+255)/256,256,0,stream>>>(d0_whh, W0h, W0l, 1024, 1024, 2560, 1536, tot);
        permute_bias_kernel<<<16,256,0,stream>>>(d0_b, b0p, 1024);
        tot = 4096*1024;
        permute_convert_split_kernel<<<(tot+255)/256,256,0,stream>>>(d1_wih, W1h, W1l, 1024, 1024, 2048, 0, tot);
        permute_convert_split_kernel<<<(tot+255)/256,256,0,stream>>>(d1_whh, W1h, W1l, 1024, 1024, 2048, 1024, tot);
        permute_bias_kernel<<<16,256,0,stream>>>(d1_b, b1p, 1024);
        int tf = 256*1024;
        convert_split_kernel<<<(tf+255)/256,256,0,stream>>>(fc_w, 1024, 0, Wch, Wcl, 1024, 1024, tf);
        int tq = 1024*1024;
        convert_split_kernel<<<(tq+255)/256,256,0,stream>>>(attn_w1, 2048, 1024,
            Wch + (size_t)256*1024, Wcl + (size_t)256*1024, 1024, 1024, tq);
        build_bcq_kernel<<<5,256,0,stream>>>(fc_b, attn_b1, bcq);
    }
    // ---- decoder init ----
    dec_init_kernel<<<1024,256,0,stream>>>(
        hbuf + 0*2*HSZ2, hbuf + 1*2*HSZ2, hbuf + 2*2*HSZ2, hbuf + 3*2*HSZ2,
        cbuf + 0*CSZ, cbuf + 1*CSZ, cbuf + 2*CSZ, cbuf + 3*CSZ,
        bufA0h, bufA0l, bufA1h, bufA1l, c0, c1);

    // initial combined: qp from initial h1 (fc part -> qdump)
    {
        DG d{};
        d.Ah = bufA1h + 1024; d.Al = bufA1l + 1024; d.lda = 2048;
        d.Bh = Wch; d.Bl = Wcl; d.K = 1024; d.bias = bcq;
        d.Cf = qdump; d.ldc = 256; d.qp = qp; d.nblk = 20;
        dgemm_kernel<1><<<80,256,0,stream>>>(d);
    }

    // ---- decoder loop: 4 full-chip kernels per step ----
    for (int n = 0; n < 127; n++){
        int pc = n & 1, pn = (n+1) & 1;
        attn2_kernel<<<256,256,0,stream>>>(enc_prj, enc_out, qp, attn_w2, attn_b2,
            src, tgt, dec_embed, out1,
            bufA0h + (size_t)pc*A0SZ, bufA0l + (size_t)pc*A0SZ, n);
        // dec l0
        {
            DG d{};
            d.Ah = bufA0h + (size_t)pc*A0SZ; d.Al = bufA0l + (size_t)pc*A0SZ; d.lda = 2560;
            d.Bh = W0h; d.Bl = W0l; d.K = 2560; d.bias = b0p;
            d.cst = c0;
            d.h1 = bufA0h + (size_t)pn*A0SZ + 1536; d.h1l = bufA0l + (size_t)pn*A0SZ + 1536; d.ldh1 = 2560;
            d.h2 = bufA1h + (size_t)pc*A1SZ;        d.h2l = bufA1l + (size_t)pc*A1SZ;        d.ldh2 = 2048;
            d.nblk = 64;
            dgemm_kernel<0><<<256,256,0,stream>>>(d);
        }
        // dec l1
        {
            DG d{};
            d.Ah = bufA1h + (size_t)pc*A1SZ; d.Al = bufA1l + (size_t)pc*A1SZ; d.lda = 2048;
            d.Bh = W1h; d.Bl = W1l; d.K = 2048; d.bias = b1p;
            d.cst = c1;
            d.h1 = bufA1h + (size_t)pn*A1SZ + 1024; d.h1l = bufA1l + (size_t)pn*A1SZ + 1024; d.ldh1 = 2048;
            d.h2 = nullptr; d.h2l = nullptr; d.ldh2 = 0;
            d.nblk = 64;
            dgemm_kernel<0><<<256,256,0,stream>>>(d);
        }
        // combined: logits -> out0[:, n+1, :], q_proj(next) -> qp
        {
            DG d{};
            d.Ah = bufA1h + (size_t)pn*A1SZ + 1024; d.Al = bufA1l + (size_t)pn*A1SZ + 1024; d.lda = 2048;
            d.Bh = Wch; d.Bl = Wcl; d.K = 1024; d.bias = bcq;
            d.Cf = out0 + (size_t)(n+1)*VV; d.ldc = (long)TT*VV; d.qp = qp; d.nblk = 20;
            dgemm_kernel<1><<<80,256,0,stream>>>(d);
        }
    }
}

// Round 8
// 24593.488 us; speedup vs baseline: 3.8671x; 1.1507x over previous
//
#include <hip/hip_runtime.h>
#include <stdint.h>

typedef unsigned short u16;
typedef __attribute__((ext_vector_type(8))) short short8;
typedef __attribute__((ext_vector_type(4))) float f32x4;

#define BB 256
#define SS 128
#define TT 128
#define EE 512
#define HH 1024
#define VV 256

#define BK 64
#define LDSP 72   // padded LDS row length in bf16 elems (144 B = 9*16, keeps 16B alignment)
#define CH 8      // encoder pre-GEMM chunk (timesteps)

__device__ __forceinline__ float bf2f(u16 u){
    union { unsigned int i; float f; } v; v.i = ((unsigned int)u) << 16; return v.f;
}
__device__ __forceinline__ u16 f2bf(float f){
    union { float f; unsigned int i; } v; v.f = f;
    return (u16)((v.i + 0x7fffu + ((v.i >> 16) & 1u)) >> 16);
}
__device__ __forceinline__ float rcp_(float x){ return __builtin_amdgcn_rcpf(x); }
__device__ __forceinline__ float sigm_(float x){ return rcp_(1.f + __expf(-x)); }
__device__ __forceinline__ float tanh_(float x){ return 1.f - 2.f*rcp_(__expf(2.f*x) + 1.f); }

struct GArgs {
    const u16* A;  const u16* A2; long lda;
    const u16* Bw; const u16* B2; long K;
    const float* bias;
    u16* Cb; float* Cf; long ldc;
    const u16* pre; long ldpre;
    float* cst; long hid;
    u16* h1; u16* h1l; long ldh1;
    u16* h2; u16* h2l; long ldh2;
};

// ===== R3-proven GEMM core — pre-GEMMs / enc_proj =====
template<int BMW, int BNW, int MODE, int SPLIT>
__device__ __forceinline__ void gemm_core(const GArgs& g)
{
    constexpr int BM = BMW*64, BN = BNW*64;
    constexpr int NT = BMW*BNW*64;
    constexpr int AE = BM*LDSP, BE = BN*LDSP;
    static_assert((BM*8) % NT == 0 && (BN*8) % NT == 0, "staging");
    __shared__ __align__(16) u16 sA[(SPLIT+1)*AE];
    __shared__ __align__(16) u16 sB[(SPLIT+1)*BE];
    const int tid = threadIdx.x;
    const int lane = tid & 63, wave = tid >> 6;
    const int wn = wave % BNW, wm = wave / BNW;
    const int l15 = lane & 15, quad = lane >> 4;
    const long m0 = (long)blockIdx.y * BM, n0 = (long)blockIdx.x * BN;

    f32x4 acc[4][4];
    #pragma unroll
    for (int a=0;a<4;a++)
    #pragma unroll
    for (int c=0;c<4;c++){ f32x4 z = {0.f,0.f,0.f,0.f}; acc[a][c] = z; }

    for (long k0 = 0; k0 < g.K; k0 += BK){
        #pragma unroll
        for (int i = 0; i < BM*8/NT; i++){
            int c = tid + i*NT;
            int r = c >> 3, c8 = (c & 7) * 8;
            *(int4*)&sA[r*LDSP + c8] = *(const int4*)(g.A + (m0 + r)*g.lda + k0 + c8);
            if (SPLIT)
                *(int4*)&sA[AE + r*LDSP + c8] = *(const int4*)(g.A2 + (m0 + r)*g.lda + k0 + c8);
        }
        #pragma unroll
        for (int i = 0; i < BN*8/NT; i++){
            int c = tid + i*NT;
            int r = c >> 3, c8 = (c & 7) * 8;
            *(int4*)&sB[r*LDSP + c8] = *(const int4*)(g.Bw + (n0 + r)*g.K + k0 + c8);
            if (SPLIT)
                *(int4*)&sB[BE + r*LDSP + c8] = *(const int4*)(g.B2 + (n0 + r)*g.K + k0 + c8);
        }
        __syncthreads();
        #pragma unroll
        for (int ks = 0; ks < 2; ks++){
            const int ko = ks*32 + quad*8;
            short8 ah[4], bh[4], al[4], bl[4];
            #pragma unroll
            for (int mi=0; mi<4; mi++){
                int ra = (wm*64 + mi*16 + l15)*LDSP + ko;
                ah[mi] = *(const short8*)&sA[ra];
                if (SPLIT) al[mi] = *(const short8*)&sA[AE + ra];
            }
            #pragma unroll
            for (int ni=0; ni<4; ni++){
                int rb = (wn*64 + ni*16 + l15)*LDSP + ko;
                bh[ni] = *(const short8*)&sB[rb];
                if (SPLIT) bl[ni] = *(const short8*)&sB[BE + rb];
            }
            #pragma unroll
            for (int mi=0; mi<4; mi++)
            #pragma unroll
            for (int ni=0; ni<4; ni++){
                acc[mi][ni] = __builtin_amdgcn_mfma_f32_16x16x32_bf16(ah[mi], bh[ni], acc[mi][ni], 0,0,0);
                if (SPLIT){
                    acc[mi][ni] = __builtin_amdgcn_mfma_f32_16x16x32_bf16(al[mi], bh[ni], acc[mi][ni], 0,0,0);
                    acc[mi][ni] = __builtin_amdgcn_mfma_f32_16x16x32_bf16(ah[mi], bl[ni], acc[mi][ni], 0,0,0);
                }
            }
        }
        __syncthreads();
    }

    #pragma unroll
    for (int mi=0; mi<4; mi++)
    #pragma unroll
    for (int ni=0; ni<4; ni++)
    #pragma unroll
    for (int r=0; r<4; r++){
        long row = m0 + wm*64 + mi*16 + quad*4 + r;
        long col = n0 + wn*64 + ni*16 + l15;
        float v = acc[mi][ni][r];
        if (g.bias) v += g.bias[col];
        if (MODE == 1){
            g.Cf[row*g.ldc + col] = v;
        } else {
            g.Cb[row*g.ldc + col] = f2bf(v);
        }
    }
}

template<int BMW,int BNW,int MODE,int SPLIT>
__global__ __launch_bounds__(BMW*BNW*64)
void gemm_kernel(GArgs g){ gemm_core<BMW,BNW,MODE,SPLIT>(g); }

template<int BMW,int BNW>
__global__ __launch_bounds__(BMW*BNW*64)
void gemm2_kernel(GArgs ga, GArgs gb){
    if (blockIdx.z == 0) gemm_core<BMW,BNW,0,0>(ga);
    else                 gemm_core<BMW,BNW,0,0>(gb);
}

// ==================== encoder scan step: full-chip, both directions ====================
struct ES {
    const u16 *A0, *A1;          // h state per dir (256 x 512)
    const u16 *Bw0, *Bw1;        // whh gate-permuted (2048 x 512)
    const float *bias0, *bias1;  // gate-permuted (2048)
    const u16 *pre0, *pre1;      // pre-activations (256 x 2048) bf16
    float *cst0, *cst1;          // c state (256 x 512) f32
    u16 *h10, *h11; long ldh1;   // primary h dest
    u16 *h20, *h21;              // hbuf next-parity dest (stride 512)
};

__global__ __launch_bounds__(256)
void enc_step_kernel(ES e)
{
    __shared__ __align__(16) u16 smem[2*64*LDSP];
    const int bid = blockIdx.x;              // 256 blocks
    const int dir = bid >> 7, rblk = bid & 127;
    const int by = rblk >> 5, bx = rblk & 31;   // M:4 x N:32 tiles of 64x64
    const u16* A  = dir ? e.A1  : e.A0;
    const u16* Bw = dir ? e.Bw1 : e.Bw0;
    const float* bias = dir ? e.bias1 : e.bias0;
    const u16* pre = dir ? e.pre1 : e.pre0;
    float* cst = dir ? e.cst1 : e.cst0;
    u16* h1 = dir ? e.h11 : e.h10;
    u16* h2 = dir ? e.h21 : e.h20;
    const long m0 = (long)by*64, n0 = (long)bx*64;
    u16* sA = smem;
    u16* sB = smem + 64*LDSP;
    const int tid = threadIdx.x;
    const int lane = tid & 63, wave = tid >> 6;
    const int wm2 = wave >> 1, wn2 = wave & 1;
    const int l15 = lane & 15, quad = lane >> 4;

    f32x4 acc[2][2];
    #pragma unroll
    for (int a=0;a<2;a++)
    #pragma unroll
    for (int c=0;c<2;c++){ f32x4 z = {0.f,0.f,0.f,0.f}; acc[a][c] = z; }

    for (int k0 = 0; k0 < 512; k0 += BK){
        #pragma unroll
        for (int i = 0; i < 2; i++){
            int idx = tid + i*256;           // 512 chunks of 8 u16 per matrix
            int r = idx >> 3, c8 = (idx & 7) * 8;
            *(int4*)&sA[r*LDSP + c8] = *(const int4*)(A  + (m0 + r)*512 + k0 + c8);
            *(int4*)&sB[r*LDSP + c8] = *(const int4*)(Bw + (n0 + r)*512 + k0 + c8);
        }
        __syncthreads();
        #pragma unroll
        for (int ks = 0; ks < 2; ks++){
            const int ko = ks*32 + quad*8;
            short8 ah[2], bh[2];
            #pragma unroll
            for (int mi=0; mi<2; mi++)
                ah[mi] = *(const short8*)&sA[(wm2*32 + mi*16 + l15)*LDSP + ko];
            #pragma unroll
            for (int ni=0; ni<2; ni++)
                bh[ni] = *(const short8*)&sB[(wn2*32 + ni*16 + l15)*LDSP + ko];
            #pragma unroll
            for (int mi=0; mi<2; mi++)
            #pragma unroll
            for (int ni=0; ni<2; ni++)
                acc[mi][ni] = __builtin_amdgcn_mfma_f32_16x16x32_bf16(ah[mi], bh[ni], acc[mi][ni], 0,0,0);
        }
        __syncthreads();
    }

    #pragma unroll
    for (int mi=0; mi<2; mi++)
    #pragma unroll
    for (int ni=0; ni<2; ni++)
    #pragma unroll
    for (int r=0; r<4; r++){
        long row = m0 + wm2*32 + mi*16 + quad*4 + r;
        long col = n0 + wn2*32 + ni*16 + l15;
        float v = acc[mi][ni][r] + bias[col] + bf2f(pre[row*2048 + col]);
        float gf = __shfl_xor(v, 1);
        float gg = __shfl_xor(v, 2);
        float go = __shfl_xor(v, 3);
        if ((lane & 3) == 0){
            long j = col >> 2;               // [0,512)
            float co = cst[row*512 + j];
            float cn = sigm_(gf)*co + sigm_(v)*tanh_(gg);
            cst[row*512 + j] = cn;
            float hn = sigm_(go)*tanh_(cn);
            u16 hb = f2bf(hn);
            h1[row*e.ldh1 + j] = hb;
            h2[row*512 + j] = hb;
        }
    }
}

// ==================== decoder phase kernels (R7, proven) ====================
struct DG {
    const u16 *Ah, *Al; long lda;
    const u16 *Bh, *Bl; long K;
    const float* bias;
    float* cst;
    u16 *h1, *h1l; long ldh1;
    u16 *h2, *h2l; long ldh2;
    float* Cf; long ldc;
    float* qp;
    int nblk;
};

template<int EPI>
__global__ __launch_bounds__(256)
void dgemm_kernel(DG d)
{
    __shared__ __align__(16) u16 smem[4*64*LDSP];
    const int bid = blockIdx.x;
    const int by = bid / d.nblk, bx = bid - by*d.nblk;
    const long m0 = (long)by*64, n0 = (long)bx*64;
    u16* sAh = smem;
    u16* sAl = smem + 64*LDSP;
    u16* sBh = smem + 2*64*LDSP;
    u16* sBl = smem + 3*64*LDSP;
    const int tid = threadIdx.x;
    const int lane = tid & 63, wave = tid >> 6;
    const int wm2 = wave >> 1, wn2 = wave & 1;
    const int l15 = lane & 15, quad = lane >> 4;

    f32x4 acc[2][2];
    #pragma unroll
    for (int a=0;a<2;a++)
    #pragma unroll
    for (int c=0;c<2;c++){ f32x4 z = {0.f,0.f,0.f,0.f}; acc[a][c] = z; }

    for (long k0 = 0; k0 < d.K; k0 += BK){
        #pragma unroll
        for (int i = 0; i < 2; i++){
            int idx = tid + i*256;
            int r = idx >> 3, c8 = (idx & 7) * 8;
            *(int4*)&sAh[r*LDSP + c8] = *(const int4*)(d.Ah + (m0 + r)*d.lda + k0 + c8);
            *(int4*)&sAl[r*LDSP + c8] = *(const int4*)(d.Al + (m0 + r)*d.lda + k0 + c8);
            *(int4*)&sBh[r*LDSP + c8] = *(const int4*)(d.Bh + (n0 + r)*d.K + k0 + c8);
            *(int4*)&sBl[r*LDSP + c8] = *(const int4*)(d.Bl + (n0 + r)*d.K + k0 + c8);
        }
        __syncthreads();
        #pragma unroll
        for (int ks = 0; ks < 2; ks++){
            const int ko = ks*32 + quad*8;
            short8 ah[2], al[2], bh[2], bl[2];
            #pragma unroll
            for (int mi=0; mi<2; mi++){
                int ra = (wm2*32 + mi*16 + l15)*LDSP + ko;
                ah[mi] = *(const short8*)&sAh[ra];
                al[mi] = *(const short8*)&sAl[ra];
            }
            #pragma unroll
            for (int ni=0; ni<2; ni++){
                int rb = (wn2*32 + ni*16 + l15)*LDSP + ko;
                bh[ni] = *(const short8*)&sBh[rb];
                bl[ni] = *(const short8*)&sBl[rb];
            }
            #pragma unroll
            for (int mi=0; mi<2; mi++)
            #pragma unroll
            for (int ni=0; ni<2; ni++){
                acc[mi][ni] = __builtin_amdgcn_mfma_f32_16x16x32_bf16(ah[mi], bh[ni], acc[mi][ni], 0,0,0);
                acc[mi][ni] = __builtin_amdgcn_mfma_f32_16x16x32_bf16(al[mi], bh[ni], acc[mi][ni], 0,0,0);
                acc[mi][ni] = __builtin_amdgcn_mfma_f32_16x16x32_bf16(ah[mi], bl[ni], acc[mi][ni], 0,0,0);
            }
        }
        __syncthreads();
    }

    #pragma unroll
    for (int mi=0; mi<2; mi++)
    #pragma unroll
    for (int ni=0; ni<2; ni++)
    #pragma unroll
    for (int r=0; r<4; r++){
        long row = m0 + wm2*32 + mi*16 + quad*4 + r;
        long col = n0 + wn2*32 + ni*16 + l15;
        float v = acc[mi][ni][r] + d.bias[col];
        if (EPI == 0){
            float gf = __shfl_xor(v, 1);
            float gg = __shfl_xor(v, 2);
            float go = __shfl_xor(v, 3);
            if ((lane & 3) == 0){
                long j = col >> 2;
                float co = d.cst[row*1024 + j];
                float cn = sigm_(gf)*co + sigm_(v)*tanh_(gg);
                d.cst[row*1024 + j] = cn;
                float hn = sigm_(go)*tanh_(cn);
                u16 hb = f2bf(hn);
                u16 lb = f2bf(hn - bf2f(hb));
                d.h1[row*d.ldh1 + j] = hb;  d.h1l[row*d.ldh1 + j] = lb;
                if (d.h2){ d.h2[row*d.ldh2 + j] = hb;  d.h2l[row*d.ldh2 + j] = lb; }
            }
        } else {
            if (col < 256) d.Cf[row*d.ldc + col] = v;
            else           d.qp[row*1024 + (col - 256)] = v;
        }
    }
}

// attention step (R6-improved: pipelined energy, unrolled ctx)
__global__ __launch_bounds__(256)
void attn2_kernel(const u16* __restrict__ enc_prj, const u16* __restrict__ enc_out,
                  const float* __restrict__ qp, const float* __restrict__ w2,
                  const float* __restrict__ b2p,
                  const int* __restrict__ src, const int* __restrict__ tgt,
                  const float* __restrict__ dec_embed,
                  float* __restrict__ out1,
                  u16* __restrict__ a0h, u16* __restrict__ a0l, int n)
{
    __shared__ float sE[SS];
    __shared__ float sAs[SS];
    const int b = blockIdx.x;
    const int tid = threadIdx.x;
    const int lane = tid & 63, wave = tid >> 6;
    float qr[16], wr[16];
    const float* qb = qp + (size_t)b*HH;
    #pragma unroll
    for (int j=0;j<8;j++){
        qr[j]   = qb[lane*8 + j];        wr[j]   = w2[lane*8 + j];
        qr[8+j] = qb[512 + lane*8 + j];  wr[8+j] = w2[512 + lane*8 + j];
    }
    float b2 = b2p[0];
    {
        const int s0 = wave*32;
        const u16* row0 = enc_prj + ((size_t)b*SS + s0)*HH;
        int4 r0 = *(const int4*)(row0 + lane*8);
        int4 r1 = *(const int4*)(row0 + 512 + lane*8);
        for (int ii=0; ii<32; ii++){
            int4 c0 = r0, c1 = r1;
            if (ii < 31){
                const u16* nr = enc_prj + ((size_t)b*SS + s0 + ii + 1)*HH;
                r0 = *(const int4*)(nr + lane*8);
                r1 = *(const int4*)(nr + 512 + lane*8);
            }
            const u16* u0 = (const u16*)&c0;
            const u16* u1 = (const u16*)&c1;
            float acc = 0.f;
            #pragma unroll
            for (int j=0;j<8;j++) acc += tanh_(bf2f(u0[j]) + qr[j]) * wr[j];
            #pragma unroll
            for (int j=0;j<8;j++) acc += tanh_(bf2f(u1[j]) + qr[8+j]) * wr[8+j];
            #pragma unroll
            for (int off=32; off; off>>=1) acc += __shfl_xor(acc, off);
            if (lane == 0){
                float e = acc + b2;
                if (src[b*SS + s0 + ii] == 0) e = -1e30f;
                sE[s0 + ii] = e;
            }
        }
    }
    __syncthreads();
    if (wave == 0){
        float v0 = sE[lane], v1 = sE[64 + lane];
        float m = fmaxf(v0, v1);
        #pragma unroll
        for (int off=32; off; off>>=1) m = fmaxf(m, __shfl_xor(m, off));
        float p0 = __expf(v0 - m), p1 = __expf(v1 - m);
        float sum = p0 + p1;
        #pragma unroll
        for (int off=32; off; off>>=1) sum += __shfl_xor(sum, off);
        float inv = 1.f / sum;
        float a0 = p0 * inv, a1 = p1 * inv;
        sAs[lane] = a0; sAs[64+lane] = a1;
        float* op = out1 + ((size_t)b*(TT-1) + n)*SS;
        op[lane] = a0; op[64+lane] = a1;
    }
    __syncthreads();
    int c4 = tid*4;
    float av0=0, av1=0, av2=0, av3=0;
    const u16* eb = enc_out + (size_t)b*SS*HH + c4;
    for (int s=0; s<SS; s+=8){
        uint2 u[8];
        #pragma unroll
        for (int k=0;k<8;k++) u[k] = *(const uint2*)(eb + (size_t)(s+k)*HH);
        #pragma unroll
        for (int k=0;k<8;k++){
            float as = sAs[s+k];
            const u16* pu = (const u16*)&u[k];
            av0 += as * bf2f(pu[0]);
            av1 += as * bf2f(pu[1]);
            av2 += as * bf2f(pu[2]);
            av3 += as * bf2f(pu[3]);
        }
    }
    u16* ch = a0h + (size_t)b*2560 + 512 + c4;
    u16* cl = a0l + (size_t)b*2560 + 512 + c4;
    float av[4] = {av0,av1,av2,av3};
    #pragma unroll
    for (int k=0;k<4;k++){
        u16 hi = f2bf(av[k]); ch[k] = hi; cl[k] = f2bf(av[k] - bf2f(hi));
    }
    int tok = tgt[b*TT + n];
    const float* ep = dec_embed + (size_t)tok*EE;
    u16* ehp = a0h + (size_t)b*2560;
    u16* elp = a0l + (size_t)b*2560;
    #pragma unroll
    for (int k=0;k<2;k++){
        int e = tid*2 + k;
        float x = ep[e];
        u16 hi = f2bf(x);
        ehp[e] = hi; elp[e] = f2bf(x - bf2f(hi));
    }
}

// ---------------- prep / utility kernels ----------------
__global__ void permute_convert_kernel(const float* __restrict__ s, u16* __restrict__ d,
    int hid, int cols, int dld, int doff, int total){
    int i = blockIdx.x*256 + threadIdx.x;
    if (i >= total) return;
    int p = i / cols, c = i - p*cols;
    int j = p >> 2, q = p & 3;
    d[(size_t)p*dld + doff + c] = f2bf(s[((size_t)q*hid + j)*cols + c]);
}
__global__ void permute_convert_split_kernel(const float* __restrict__ s, u16* __restrict__ dh,
    u16* __restrict__ dl, int hid, int cols, int dld, int doff, int total){
    int i = blockIdx.x*256 + threadIdx.x;
    if (i >= total) return;
    int p = i / cols, c = i - p*cols;
    int j = p >> 2, q = p & 3;
    float x = s[((size_t)q*hid + j)*cols + c];
    u16 hi = f2bf(x);
    dh[(size_t)p*dld + doff + c] = hi;
    dl[(size_t)p*dld + doff + c] = f2bf(x - bf2f(hi));
}
__global__ void permute_bias_kernel(const float* __restrict__ s, float* __restrict__ d, int hid){
    int p = blockIdx.x*256 + threadIdx.x;
    if (p >= 4*hid) return;
    int j = p >> 2, q = p & 3;
    d[p] = s[q*hid + j];
}
__global__ void convert_kernel(const float* __restrict__ s, int sld, int soff,
    u16* __restrict__ d, int dld, int cols, int total){
    int i = blockIdx.x*256 + threadIdx.x;
    if (i >= total) return;
    int r = i / cols, c = i - r*cols;
    d[(size_t)r*dld + c] = f2bf(s[(size_t)r*sld + soff + c]);
}
__global__ void convert_split_kernel(const float* __restrict__ s, int sld, int soff,
    u16* __restrict__ dh, u16* __restrict__ dl, int dld, int cols, int total){
    int i = blockIdx.x*256 + threadIdx.x;
    if (i >= total) return;
    int r = i / cols, c = i - r*cols;
    float x = s[(size_t)r*sld + soff + c];
    u16 hi = f2bf(x);
    dh[(size_t)r*dld + c] = hi;
    dl[(size_t)r*dld + c] = f2bf(x - bf2f(hi));
}
__global__ void build_bcq_kernel(const float* __restrict__ fcb, const float* __restrict__ ab1,
    float* __restrict__ d){
    int i = blockIdx.x*256 + threadIdx.x;
    if (i < 256) d[i] = fcb[i];
    else if (i < 1280) d[i] = ab1[i - 256];
}
__global__ void gather_chunk_kernel(const int* __restrict__ src, const float* __restrict__ emb,
    u16* __restrict__ xe, int t0){
    int i = blockIdx.x*256 + threadIdx.x;
    int m = i >> 9, e = i & 511;
    int tl = m >> 8, b = m & 255;
    int tok = src[b*SS + t0 + tl];
    xe[i] = f2bf(emb[(size_t)tok*EE + e]);
}
__global__ void zero_u16_kernel(u16* p, int n){
    int i = blockIdx.x*256 + threadIdx.x; if (i < n) p[i] = 0;
}
__global__ void zero_f32_kernel(float* p, int n){
    int i = blockIdx.x*256 + threadIdx.x; if (i < n) p[i] = 0.f;
}
__global__ void zero_out0_kernel(float* out0){
    int i = blockIdx.x*256 + threadIdx.x;
    int b = i >> 8, v = i & 255;
    out0[(size_t)b*TT*VV + v] = 0.f;
}
__global__ void dec_init_kernel(const u16* h0f, const u16* h0b, const u16* h1f, const u16* h1b,
    const float* c0f, const float* c0b, const float* c1f, const float* c1b,
    u16* a0h, u16* a0l, u16* a1h, u16* a1l, float* c0, float* c1)
{
    int i = blockIdx.x*256 + threadIdx.x;
    int m = i >> 10, j = i & 1023;
    u16 h0 = (j < 512) ? h0f[m*512 + j] : h0b[m*512 + j - 512];
    u16 h1 = (j < 512) ? h1f[m*512 + j] : h1b[m*512 + j - 512];
    float cc0 = (j < 512) ? c0f[m*512 + j] : c0b[m*512 + j - 512];
    float cc1 = (j < 512) ? c1f[m*512 + j] : c1b[m*512 + j - 512];
    a0h[(size_t)m*2560 + 1536 + j] = h0; a0l[(size_t)m*2560 + 1536 + j] = 0;
    a1h[(size_t)m*2048 + 1024 + j] = h1; a1l[(size_t)m*2048 + 1024 + j] = 0;
    c0[i] = cc0; c1[i] = cc1;
}

// ---------------- host ----------------
extern "C" void kernel_launch(void* const* d_in, const int* in_sizes, int n_in,
                              void* d_out, int out_size, void* d_ws, size_t ws_size,
                              hipStream_t stream)
{
    (void)in_sizes; (void)n_in; (void)out_size;
    const size_t NEED = 230100000;
    if (ws_size < NEED) return;

    const int*   src = (const int*)d_in[0];
    const int*   tgt = (const int*)d_in[1];
    const float* enc_embed = (const float*)d_in[2];
    const float* dec_embed = (const float*)d_in[3];
    const float* ew[4][3] = {
        {(const float*)d_in[4],  (const float*)d_in[5],  (const float*)d_in[6]},
        {(const float*)d_in[7],  (const float*)d_in[8],  (const float*)d_in[9]},
        {(const float*)d_in[10], (const float*)d_in[11], (const float*)d_in[12]},
        {(const float*)d_in[13], (const float*)d_in[14], (const float*)d_in[15]},
    };
    const float* d0_wih = (const float*)d_in[16];
    const float* d0_whh = (const float*)d_in[17];
    const float* d0_b   = (const float*)d_in[18];
    const float* d1_wih = (const float*)d_in[19];
    const float* d1_whh = (const float*)d_in[20];
    const float* d1_b   = (const float*)d_in[21];
    const float* attn_w1 = (const float*)d_in[22];
    const float* attn_b1 = (const float*)d_in[23];
    const float* attn_w2 = (const float*)d_in[24];
    const float* attn_b2 = (const float*)d_in[25];
    const float* fc_w = (const float*)d_in[26];
    const float* fc_b = (const float*)d_in[27];

    float* out0 = (float*)d_out;
    float* out1 = out0 + (size_t)BB*TT*VV;

    char* base = (char*)d_ws;
    size_t off = 0;
    auto alloc = [&](size_t nbytes)->char*{
        char* p = base + off;
        off += (nbytes + 255) & ~(size_t)255;
        return p;
    };
    float* b_e[4];
    for (int d2=0; d2<4; d2++) b_e[d2] = (float*)alloc(2048*4);
    float* b0p = (float*)alloc(4096*4);
    float* b1p = (float*)alloc(4096*4);
    float* bcq = (float*)alloc(1280*4);
    u16* hbuf    = (u16*)alloc((size_t)8*256*512*2);
    float* cbuf  = (float*)alloc((size_t)4*256*512*4);
    u16* bufA0h = (u16*)alloc((size_t)2*256*2560*2);
    u16* bufA0l = (u16*)alloc((size_t)2*256*2560*2);
    u16* bufA1h = (u16*)alloc((size_t)2*256*2048*2);
    u16* bufA1l = (u16*)alloc((size_t)2*256*2048*2);
    float* c0 = (float*)alloc((size_t)256*1024*4);
    float* c1 = (float*)alloc((size_t)256*1024*4);
    float* qp = (float*)alloc((size_t)256*1024*4);
    float* qdump = (float*)alloc((size_t)256*256*4);
    u16* enc_out = (u16*)alloc((size_t)32768*1024*2);
    u16* x1      = (u16*)alloc((size_t)32768*1024*2);
    u16* enc_prj = x1;
    char* D = alloc(81000000);
    size_t doff = 0;
    auto carve = [&](size_t nbytes)->char*{ char* p = D + doff; doff += nbytes; return p; };
    const int in_dim_e[4] = {512,512,1024,1024};
    u16* wih_e[4]; u16* whh_e[4];
    for (int d2=0; d2<4; d2++){
        wih_e[d2] = (u16*)carve((size_t)2048*in_dim_e[d2]*2);
        whh_e[d2] = (u16*)carve((size_t)2048*512*2);
    }
    u16* w1enc = (u16*)carve((size_t)1024*1024*2);
    u16* xef   = (u16*)carve((size_t)CH*256*512*2);
    u16* xeb   = (u16*)carve((size_t)CH*256*512*2);
    u16* preA  = (u16*)carve((size_t)CH*256*2048*2);
    u16* preB  = (u16*)carve((size_t)CH*256*2048*2);
    doff = 0;
    u16* W0h = (u16*)carve((size_t)4096*2560*2);
    u16* W0l = (u16*)carve((size_t)4096*2560*2);
    u16* W1h = (u16*)carve((size_t)4096*2048*2);
    u16* W1l = (u16*)carve((size_t)4096*2048*2);
    u16* Wch = (u16*)carve((size_t)1280*1024*2);
    u16* Wcl = (u16*)carve((size_t)1280*1024*2);

    const size_t HSZ2 = 256*512;
    const size_t CSZ  = 256*512;
    const size_t A0SZ = 256*2560, A1SZ = 256*2048;

    // ---- encoder weight prep ----
    for (int d2=0; d2<4; d2++){
        int tot = 2048*in_dim_e[d2];
        permute_convert_kernel<<<(tot+255)/256,256,0,stream>>>(ew[d2][0], wih_e[d2], 512, in_dim_e[d2], in_dim_e[d2], 0, tot);
        tot = 2048*512;
        permute_convert_kernel<<<(tot+255)/256,256,0,stream>>>(ew[d2][1], whh_e[d2], 512, 512, 512, 0, tot);
        permute_bias_kernel<<<8,256,0,stream>>>(ew[d2][2], b_e[d2], 512);
    }
    {
        int tw = 1024*1024;
        convert_kernel<<<(tw+255)/256,256,0,stream>>>(attn_w1, 2048, 0, w1enc, 1024, 1024, tw);
    }
    for (int d2=0; d2<4; d2++)
        zero_u16_kernel<<<512,256,0,stream>>>(hbuf + (size_t)(d2*2)*HSZ2, (int)HSZ2);
    zero_f32_kernel<<<2048,256,0,stream>>>(cbuf, 4*(int)CSZ);
    zero_out0_kernel<<<256,256,0,stream>>>(out0);

    // ---- encoder: chunked pre-GEMMs interleaved with full-chip scan steps ----
    for (int layer = 0; layer < 2; layer++){
        const long ldx  = layer ? 1024 : 512;
        const int  dirf = layer*2, dirb = layer*2 + 1;
        for (int c = 0; c < 128/CH; c++){
            const int tf0 = c*CH, tb0 = 128 - CH*(c+1);
            const u16 *Af, *Ab;
            if (layer == 0){
                gather_chunk_kernel<<<CH*512,256,0,stream>>>(src, enc_embed, xef, tf0);
                gather_chunk_kernel<<<CH*512,256,0,stream>>>(src, enc_embed, xeb, tb0);
                Af = xef; Ab = xeb;
            } else {
                Af = x1 + (size_t)tf0*256*1024;
                Ab = x1 + (size_t)tb0*256*1024;
            }
            {
                GArgs a{}, b{};
                a.A = Af; a.lda = ldx; a.Bw = wih_e[dirf]; a.K = ldx; a.bias = b_e[dirf];
                a.Cb = preA; a.ldc = 2048;
                b.A = Ab; b.lda = ldx; b.Bw = wih_e[dirb]; b.K = ldx; b.bias = b_e[dirb];
                b.Cb = preB; b.ldc = 2048;
                gemm2_kernel<2,2><<<dim3(16, CH*2, 2),256,0,stream>>>(a, b);
            }
            for (int i = 0; i < CH; i++){
                int t = c*CH + i;
                ES e{};
                e.A0 = hbuf + (size_t)(dirf*2 + (t&1))*HSZ2;
                e.A1 = hbuf + (size_t)(dirb*2 + (t&1))*HSZ2;
                e.Bw0 = whh_e[dirf];  e.Bw1 = whh_e[dirb];
                e.bias0 = b_e[dirf];  e.bias1 = b_e[dirb];
                e.pre0 = preA + (size_t)i*256*2048;
                e.pre1 = preB + (size_t)(CH-1-i)*256*2048;
                e.cst0 = cbuf + (size_t)dirf*CSZ;
                e.cst1 = cbuf + (size_t)dirb*CSZ;
                if (layer == 0){
                    e.h10 = x1 + (size_t)t*256*1024;
                    e.h11 = x1 + (size_t)(127-t)*256*1024 + 512;
                    e.ldh1 = 1024;
                } else {
                    e.h10 = enc_out + (size_t)t*1024;
                    e.h11 = enc_out + (size_t)(127-t)*1024 + 512;
                    e.ldh1 = (long)SS*1024;
                }
                e.h20 = hbuf + (size_t)(dirf*2 + ((t+1)&1))*HSZ2;
                e.h21 = hbuf + (size_t)(dirb*2 + ((t+1)&1))*HSZ2;
                enc_step_kernel<<<256,256,0,stream>>>(e);
            }
        }
    }
    // ---- enc_proj = enc_out @ w1_enc^T ----
    {
        GArgs a{}; a.A = enc_out; a.lda = 1024; a.Bw = w1enc; a.K = 1024;
        a.Cb = enc_prj; a.ldc = 1024;
        gemm_kernel<2,2,0,0><<<dim3(8,256),256,0,stream>>>(a);
    }
    // ---- decoder weight prep ----
    {
        int tot = 4096*1536;
        permute_convert_split_kernel<<<(tot+255)/256,256,0,stream>>>(d0_wih, W0h, W0l, 1024, 1536, 2560, 0, tot);
        tot = 4096*1024;
        permute_convert_split_kernel<<<(tot+255)/256,256,0,stream>>>(d0_whh, W0h, W0l, 1024, 1024, 2560, 1536, tot);
        permute_bias_kernel<<<16,256,0,stream>>>(d0_b, b0p, 1024);
        tot = 4096*1024;
        permute_convert_split_kernel<<<(tot+255)/256,256,0,stream>>>(d1_wih, W1h, W1l, 1024, 1024, 2048, 0, tot);
        permute_convert_split_kernel<<<(tot+255)/256,256,0,stream>>>(d1_whh, W1h, W1l, 1024, 1024, 2048, 1024, tot);
        permute_bias_kernel<<<16,256,0,stream>>>(d1_b, b1p, 1024);
        int tf = 256*1024;
        convert_split_kernel<<<(tf+255)/256,256,0,stream>>>(fc_w, 1024, 0, Wch, Wcl, 1024, 1024, tf);
        int tq = 1024*1024;
        convert_split_kernel<<<(tq+255)/256,256,0,stream>>>(attn_w1, 2048, 1024,
            Wch + (size_t)256*1024, Wcl + (size_t)256*1024, 1024, 1024, tq);
        build_bcq_kernel<<<5,256,0,stream>>>(fc_b, attn_b1, bcq);
    }
    // ---- decoder init ----
    dec_init_kernel<<<1024,256,0,stream>>>(
        hbuf + 0*2*HSZ2, hbuf + 1*2*HSZ2, hbuf + 2*2*HSZ2, hbuf + 3*2*HSZ2,
        cbuf + 0*CSZ, cbuf + 1*CSZ, cbuf + 2*CSZ, cbuf + 3*CSZ,
        bufA0h, bufA0l, bufA1h, bufA1l, c0, c1);

    // initial combined: qp from initial h1 (fc part -> qdump)
    {
        DG d{};
        d.Ah = bufA1h + 1024; d.Al = bufA1l + 1024; d.lda = 2048;
        d.Bh = Wch; d.Bl = Wcl; d.K = 1024; d.bias = bcq;
        d.Cf = qdump; d.ldc = 256; d.qp = qp; d.nblk = 20;
        dgemm_kernel<1><<<80,256,0,stream>>>(d);
    }

    // ---- decoder loop: 4 full-chip kernels per step ----
    for (int n = 0; n < 127; n++){
        int pc = n & 1, pn = (n+1) & 1;
        attn2_kernel<<<256,256,0,stream>>>(enc_prj, enc_out, qp, attn_w2, attn_b2,
            src, tgt, dec_embed, out1,
            bufA0h + (size_t)pc*A0SZ, bufA0l + (size_t)pc*A0SZ, n);
        {
            DG d{};
            d.Ah = bufA0h + (size_t)pc*A0SZ; d.Al = bufA0l + (size_t)pc*A0SZ; d.lda = 2560;
            d.Bh = W0h; d.Bl = W0l; d.K = 2560; d.bias = b0p;
            d.cst = c0;
            d.h1 = bufA0h + (size_t)pn*A0SZ + 1536; d.h1l = bufA0l + (size_t)pn*A0SZ + 1536; d.ldh1 = 2560;
            d.h2 = bufA1h + (size_t)pc*A1SZ;        d.h2l = bufA1l + (size_t)pc*A1SZ;        d.ldh2 = 2048;
            d.nblk = 64;
            dgemm_kernel<0><<<256,256,0,stream>>>(d);
        }
        {
            DG d{};
            d.Ah = bufA1h + (size_t)pc*A1SZ; d.Al = bufA1l + (size_t)pc*A1SZ; d.lda = 2048;
            d.Bh = W1h; d.Bl = W1l; d.K = 2048; d.bias = b1p;
            d.cst = c1;
            d.h1 = bufA1h + (size_t)pn*A1SZ + 1024; d.h1l = bufA1l + (size_t)pn*A1SZ + 1024; d.ldh1 = 2048;
            d.h2 = nullptr; d.h2l = nullptr; d.ldh2 = 0;
            d.nblk = 64;
            dgemm_kernel<0><<<256,256,0,stream>>>(d);
        }
        {
            DG d{};
            d.Ah = bufA1h + (size_t)pn*A1SZ + 1024; d.Al = bufA1l + (size_t)pn*A1SZ + 1024; d.lda = 2048;
            d.Bh = Wch; d.Bl = Wcl; d.K = 1024; d.bias = bcq;
            d.Cf = out0 + (size_t)(n+1)*VV; d.ldc = (long)TT*VV; d.qp = qp; d.nblk = 20;
            dgemm_kernel<1><<<80,256,0,stream>>>(d);
        }
    }
}